// Round 7
// baseline (1118.905 us; speedup 1.0000x reference)
//
#include <hip/hip_runtime.h>
#include <cstdint>
#include <cstddef>

#define M_TOK 8192
#define DIMM  512
#define HEADS 8
#define DH    64
#define MLPD  2048
#define DEPTH 6

typedef unsigned short u16;
typedef unsigned int   u32;
typedef __attribute__((ext_vector_type(8))) short short8;   // 8 bf16 (4 VGPRs)
typedef __attribute__((ext_vector_type(4))) float f32x4;    // 4 fp32 acc

__device__ __forceinline__ float bf2f(u16 u){ return __uint_as_float(((u32)u) << 16); }
__device__ __forceinline__ u16 f2bf(float f){
    u32 x = __float_as_uint(f);
    u32 r = x + 0x7fffu + ((x >> 16) & 1u);   // RNE
    return (u16)(r >> 16);
}
// packed f32x2 -> bf16x2 (RNE), 1 instr for 2 converts
__device__ __forceinline__ u32 cvt_pk_bf16(float a, float b){
    u32 r;
    asm("v_cvt_pk_bf16_f32 %0, %1, %2" : "=v"(r) : "v"(a), "v"(b));
    return r;
}
// async global->LDS, 16B per lane; lds dest wave-uniform base (+lane*16 implicit); global addr per-lane
__device__ __forceinline__ void async16(const u16* g, u16* l){
    __builtin_amdgcn_global_load_lds(
        (const __attribute__((address_space(1))) void*)(uintptr_t)(const void*)g,
        (__attribute__((address_space(3))) void*)(u32)(uintptr_t)(void*)l,
        16, 0, 0);
}
// XCD-grouping block swizzle: put all x-blocks sharing an A-row-panel on one XCD.
__device__ __forceinline__ void xcd_swizzle(int& bx, int& by){
    int nbx = gridDim.x, nby = gridDim.y;
    if ((nby & 7) == 0){
        int i = by * nbx + bx;
        int xcd = i & 7, j = i >> 3, ypg = nby >> 3;
        int yq = j / nbx;
        by = xcd * ypg + yq;
        bx = j - yq * nbx;
    }
}

// ---------------- weight transpose + cvt: fp32 in[R][C] -> bf16 out[C][R], z layers ----------------
__global__ void k_transpose_cvt(const float* __restrict__ in, u16* __restrict__ out, int R, int C){
    __shared__ u16 tile[32][33];
    size_t zoff = (size_t)blockIdx.z * R * C;
    in += zoff; out += zoff;
    int c0 = blockIdx.x * 32, r0 = blockIdx.y * 32;
    int tx = threadIdx.x, ty = threadIdx.y;           // (32, 8)
    #pragma unroll
    for (int i = 0; i < 32; i += 8)
        tile[ty + i][tx] = f2bf(in[(size_t)(r0 + ty + i) * C + c0 + tx]);
    __syncthreads();
    #pragma unroll
    for (int i = 0; i < 32; i += 8)
        out[(size_t)(c0 + ty + i) * R + r0 + tx] = tile[tx][ty + i];
}

// ---------------- LayerNorm: fp32 x row -> bf16 out; 4 rows/block, 1 wave/row ----------------
__global__ __launch_bounds__(256) void k_layernorm(const float* __restrict__ x,
                                                   const float* __restrict__ s,
                                                   const float* __restrict__ b,
                                                   u16* __restrict__ out){
    int row = blockIdx.x * 4 + (threadIdx.x >> 6);
    int lane = threadIdx.x & 63;
    const float* xp = x + (size_t)row * DIMM + lane * 8;
    float v[8];
    #pragma unroll
    for (int c = 0; c < 8; c++) v[c] = xp[c];
    float sum = 0.f, sq = 0.f;
    #pragma unroll
    for (int c = 0; c < 8; c++){ sum += v[c]; sq += v[c] * v[c]; }
    #pragma unroll
    for (int m = 32; m >= 1; m >>= 1){
        sum += __shfl_xor(sum, m);
        sq  += __shfl_xor(sq,  m);
    }
    float mu  = sum * (1.f / DIMM);
    float var = sq * (1.f / DIMM) - mu * mu;
    float rs  = rsqrtf(var + 1e-5f);
    u16* op = out + (size_t)row * DIMM + lane * 8;
    #pragma unroll
    for (int c = 0; c < 8; c++){
        int col = lane * 8 + c;
        op[c] = f2bf((v[c] - mu) * rs * s[col] + b[col]);
    }
}

// Abramowitz-Stegun 7.1.26 erf (abs err 1.5e-7): rcp + 5 FMA + exp2, no branches.
__device__ __forceinline__ float erf_as(float x){
    float ax = fabsf(x);
    float t  = __builtin_amdgcn_rcpf(fmaf(0.3275911f, ax, 1.f));
    float y  = fmaf(fmaf(fmaf(fmaf(1.061405429f, t, -1.453152027f), t,
                              1.421413741f), t, -0.284496736f), t, 0.254829592f) * t;
    float e  = exp2f(-ax * ax * 1.4426950408889634f);
    float r  = 1.f - y * e;
    return copysignf(r, x);
}
__device__ __forceinline__ float gelu_exact(float v){
    return 0.5f * v * (1.f + erf_as(v * 0.70710678118654752f));
}

#define LDT64 72   // padded stride for epilogue LDS scratch only

// ============ 128x128-tile GEMM, BK=64, dbuf + counted-vmcnt raw-barrier pipeline + T2 swizzle ========
// (unchanged from round 6 — verified)
template<int MODE>
__global__ __launch_bounds__(256) void k_gemm128b(const u16* __restrict__ A,
                                                  const u16* __restrict__ Bt,
                                                  const float* __restrict__ bias,
                                                  u16* __restrict__ Cout,
                                                  int M, int N, int K){
    __shared__ u16 As[2][128 * 64];
    __shared__ u16 Bs[2][128 * 64];
    int bx = blockIdx.x, by = blockIdx.y;
    xcd_swizzle(bx, by);
    int m0 = by * 128, n0 = bx * 128;
    int t = threadIdx.x;
    int w = t >> 6, lane = t & 63;
    int mi = lane & 15, quad = lane >> 4;
    int wr = w >> 1, wc = w & 1;
    int sw = mi & 7;                      // read-side XOR key (row&7 == mi&7 for fragment rows)

    int grow = lane >> 3;
    int gcol = (((lane & 7) ^ grow) & 7) * 8;
    const u16* agl = A  + (size_t)(m0 + w * 32 + grow) * K + gcol;
    const u16* bgl = Bt + (size_t)(n0 + w * 32 + grow) * K + gcol;

    f32x4 acc[4][4];
    #pragma unroll
    for (int mt = 0; mt < 4; mt++)
        #pragma unroll
        for (int nt = 0; nt < 4; nt++) acc[mt][nt] = (f32x4){0.f, 0.f, 0.f, 0.f};

    int nt_k = K >> 6;
    {   // prologue: stage tile 0 -> buf 0 (8 loads/wave in flight)
        u16* asl = &As[0][(w * 32) * 64];
        u16* bsl = &Bs[0][(w * 32) * 64];
        #pragma unroll
        for (int i = 0; i < 4; i++){
            async16(agl + (size_t)(i * 8) * K, asl + i * 8 * 64);
            async16(bgl + (size_t)(i * 8) * K, bsl + i * 8 * 64);
        }
    }

    for (int td = 0; td < nt_k; td++){
        int cur = td & 1;
        if (td + 1 < nt_k){                    // stage next tile, then wait ONLY for tile td
            int k0 = (td + 1) << 6;
            u16* asl = &As[cur ^ 1][(w * 32) * 64];
            u16* bsl = &Bs[cur ^ 1][(w * 32) * 64];
            #pragma unroll
            for (int i = 0; i < 4; i++){
                async16(agl + (size_t)(i * 8) * K + k0, asl + i * 8 * 64);
                async16(bgl + (size_t)(i * 8) * K + k0, bsl + i * 8 * 64);
            }
            asm volatile("s_waitcnt vmcnt(8)" ::: "memory");
        } else {
            asm volatile("s_waitcnt vmcnt(0)" ::: "memory");
        }
        __builtin_amdgcn_s_barrier();          // all waves' tile-td loads landed
        __builtin_amdgcn_sched_barrier(0);
        const u16* Ab = &As[cur][0];
        const u16* Bb = &Bs[cur][0];
        #pragma unroll
        for (int kk = 0; kk < 64; kk += 32){
            const int kc = kk >> 3;            // logical chunk base: 0 or 4
            short8 af[4], bf[4];
            #pragma unroll
            for (int mt = 0; mt < 4; mt++)
                af[mt] = *(const short8*)&Ab[(wr * 64 + mt * 16 + mi) * 64 + (((quad + kc) ^ sw) * 8)];
            #pragma unroll
            for (int nt = 0; nt < 4; nt++)
                bf[nt] = *(const short8*)&Bb[(wc * 64 + nt * 16 + mi) * 64 + (((quad + kc) ^ sw) * 8)];
            #pragma unroll
            for (int mt = 0; mt < 4; mt++)
                #pragma unroll
                for (int nt = 0; nt < 4; nt++)
                    acc[mt][nt] = __builtin_amdgcn_mfma_f32_16x16x32_bf16(af[mt], bf[nt], acc[mt][nt], 0, 0, 0);
        }
        __builtin_amdgcn_sched_barrier(0);
        __builtin_amdgcn_s_barrier();          // all reads of buf[cur] done -> safe to overwrite next iter
    }

    // ---- coalesced epilogue: per-wave C-subtile through LDS (wave-private scratch over As) ----
    float bv[4];
    if (MODE == 1){
        #pragma unroll
        for (int nt = 0; nt < 4; nt++) bv[nt] = bias[n0 + wc * 64 + nt * 16 + mi];
    }
    u16* cs = ((u16*)As) + w * 16 * LDT64;     // 16x72 u16 per wave
    int erow = lane >> 2, ecol = (lane & 3) * 16;
    #pragma unroll
    for (int mt = 0; mt < 4; mt++){
        #pragma unroll
        for (int nt = 0; nt < 4; nt++)
            #pragma unroll
            for (int r = 0; r < 4; r++){
                float v = acc[mt][nt][r];
                if (MODE == 1) v = gelu_exact(v + bv[nt]);
                cs[(quad * 4 + r) * LDT64 + nt * 16 + mi] = f2bf(v);
            }
        uint4 c0 = *(const uint4*)&cs[erow * LDT64 + ecol];
        uint4 c1 = *(const uint4*)&cs[erow * LDT64 + ecol + 8];
        u16* cp = Cout + (size_t)(m0 + wr * 64 + mt * 16 + erow) * N + n0 + wc * 64 + ecol;
        *(uint4*)cp       = c0;
        *(uint4*)(cp + 8) = c1;
    }
}

// ============ 128x128-tile GEMM, same pipeline+swizzle, fp32 residual RMW epilogue (unchanged) ========
__global__ __launch_bounds__(256) void k_gemm128_res(const u16* __restrict__ A,
                                                     const u16* __restrict__ Bt,
                                                     const float* __restrict__ bias,
                                                     float* __restrict__ xres,
                                                     int M, int N, int K){
    __shared__ u16 As[2][128 * 64];
    __shared__ u16 Bs[2][128 * 64];
    int bx = blockIdx.x, by = blockIdx.y;
    xcd_swizzle(bx, by);
    int m0 = by * 128, n0 = bx * 128;
    int t = threadIdx.x;
    int w = t >> 6, lane = t & 63;
    int mi = lane & 15, quad = lane >> 4;
    int wr = w >> 1, wc = w & 1;
    int sw = mi & 7;

    int grow = lane >> 3;
    int gcol = (((lane & 7) ^ grow) & 7) * 8;
    const u16* agl = A  + (size_t)(m0 + w * 32 + grow) * K + gcol;
    const u16* bgl = Bt + (size_t)(n0 + w * 32 + grow) * K + gcol;

    f32x4 acc[4][4];
    #pragma unroll
    for (int mt = 0; mt < 4; mt++)
        #pragma unroll
        for (int nt = 0; nt < 4; nt++) acc[mt][nt] = (f32x4){0.f, 0.f, 0.f, 0.f};

    int nt_k = K >> 6;
    {   // prologue
        u16* asl = &As[0][(w * 32) * 64];
        u16* bsl = &Bs[0][(w * 32) * 64];
        #pragma unroll
        for (int i = 0; i < 4; i++){
            async16(agl + (size_t)(i * 8) * K, asl + i * 8 * 64);
            async16(bgl + (size_t)(i * 8) * K, bsl + i * 8 * 64);
        }
    }

    for (int td = 0; td < nt_k; td++){
        int cur = td & 1;
        if (td + 1 < nt_k){
            int k0 = (td + 1) << 6;
            u16* asl = &As[cur ^ 1][(w * 32) * 64];
            u16* bsl = &Bs[cur ^ 1][(w * 32) * 64];
            #pragma unroll
            for (int i = 0; i < 4; i++){
                async16(agl + (size_t)(i * 8) * K + k0, asl + i * 8 * 64);
                async16(bgl + (size_t)(i * 8) * K + k0, bsl + i * 8 * 64);
            }
            asm volatile("s_waitcnt vmcnt(8)" ::: "memory");
        } else {
            asm volatile("s_waitcnt vmcnt(0)" ::: "memory");
        }
        __builtin_amdgcn_s_barrier();
        __builtin_amdgcn_sched_barrier(0);
        const u16* Ab = &As[cur][0];
        const u16* Bb = &Bs[cur][0];
        #pragma unroll
        for (int kk = 0; kk < 64; kk += 32){
            const int kc = kk >> 3;
            short8 af[4], bf[4];
            #pragma unroll
            for (int mt = 0; mt < 4; mt++)
                af[mt] = *(const short8*)&Ab[(wr * 64 + mt * 16 + mi) * 64 + (((quad + kc) ^ sw) * 8)];
            #pragma unroll
            for (int nt = 0; nt < 4; nt++)
                bf[nt] = *(const short8*)&Bb[(wc * 64 + nt * 16 + mi) * 64 + (((quad + kc) ^ sw) * 8)];
            #pragma unroll
            for (int mt = 0; mt < 4; mt++)
                #pragma unroll
                for (int nt = 0; nt < 4; nt++)
                    acc[mt][nt] = __builtin_amdgcn_mfma_f32_16x16x32_bf16(af[mt], bf[nt], acc[mt][nt], 0, 0, 0);
        }
        __builtin_amdgcn_sched_barrier(0);
        __builtin_amdgcn_s_barrier();
    }

    // ---- coalesced fp32 RMW epilogue through LDS (per-wave 16x72 fp32 region over As) ----
    float bv[4];
    #pragma unroll
    for (int nt = 0; nt < 4; nt++) bv[nt] = bias[n0 + wc * 64 + nt * 16 + mi];
    float* cs = ((float*)As) + w * 16 * LDT64;
    int erow = lane >> 2, ecol = (lane & 3) * 16;
    #pragma unroll
    for (int mt = 0; mt < 4; mt++){
        #pragma unroll
        for (int nt = 0; nt < 4; nt++)
            #pragma unroll
            for (int r = 0; r < 4; r++)
                cs[(quad * 4 + r) * LDT64 + nt * 16 + mi] = acc[mt][nt][r] + bv[nt];
        float* xp = xres + (size_t)(m0 + wr * 64 + mt * 16 + erow) * N + n0 + wc * 64 + ecol;
        #pragma unroll
        for (int j = 0; j < 4; j++){
            float4 cv = *(const float4*)&cs[erow * LDT64 + ecol + j * 4];
            float4 xv = *(const float4*)(xp + j * 4);
            xv.x += cv.x; xv.y += cv.y; xv.z += cv.z; xv.w += cv.w;
            *(float4*)(xp + j * 4) = xv;
        }
    }
}

// ---------------- MFMA flash attention ----------------
#define LDK 72
#define C1_LOG2E 0.18033688011112042f   // 0.125 * log2(e)
#define C2_LOG2E 11.541560327111707f    // 8 * log2(e)
#define OSPLIT (M_TOK * 512)            // elems per split O buffer (bf16)
#define LSPLIT (M_TOK * 8)              // floats per split l buffer

// split-K flash: grid 1024 (2 splits x 512); fixed-max softmax => partials combine exactly.
// Partial O stored as bf16 (pre-division; |O/l|~1 => bf16 rounding ~2e-3 abs, well under tolerance).
// l via constant-ones REGISTER B-fragment MFMA (no Vt ones rows, no lb LDS reads).
__global__ __launch_bounds__(256) void k_flash_split(const u16* __restrict__ qkv,
                                                     u16* __restrict__ Opart,
                                                     float* __restrict__ lpart){
    __shared__ u16 Ks[64 * LDK];        // [key][dim]
    __shared__ u16 Vt[64 * LDK];        // [dim][key]
    __shared__ u16 Ps[4][32 * LDK];     // per-wave P [q32][key]
    // XCD swizzle: nwg=1024, cpx=128 -> XCD k owns batch k (both splits co-located)
    int wg = (blockIdx.x & 7) * 128 + (blockIdx.x >> 3);
    int qt = wg & 7, h = (wg >> 3) & 7, sp = (wg >> 6) & 1, b = wg >> 7;
    int t = threadIdx.x;
    int w = t >> 6, lane = t & 63;
    int mi = lane & 15, quad = lane >> 4;

    const u16* base = qkv + ((size_t)b * 1024) * 1536;
    int hoff = h * 64;

    short8 ones;
    #pragma unroll
    for (int i = 0; i < 8; i++) ones[i] = (short)0x3F80;   // bf16 1.0

    short8 qf[2][2];
    #pragma unroll
    for (int qh = 0; qh < 2; qh++){
        int qrow = qt * 128 + w * 32 + qh * 16 + mi;
        const u16* qp = base + (size_t)qrow * 1536 + hoff + quad * 8;
        qf[qh][0] = *(const short8*)(qp);
        qf[qh][1] = *(const short8*)(qp + 32);
    }

    f32x4 o[2][4];
    f32x4 lacc[2];
    #pragma unroll
    for (int qh = 0; qh < 2; qh++){
        #pragma unroll
        for (int nb = 0; nb < 4; nb++) o[qh][nb] = (f32x4){0.f, 0.f, 0.f, 0.f};
        lacc[qh] = (f32x4){0.f, 0.f, 0.f, 0.f};
    }

    int kkey = t >> 2, kseg = t & 3;
    const u16* kgp = base + (size_t)kkey * 1536 + 512 + hoff + kseg * 16;
    int vkey = lane, vdg = w;
    const u16* vgp = base + (size_t)vkey * 1536 + 1024 + hoff + vdg * 16;

    int kt0 = sp * 8;
    size_t koff0 = (size_t)kt0 * 64 * 1536;
    uint4 kv0 = *(const uint4*)(kgp + koff0);
    uint4 kv1 = *(const uint4*)(kgp + koff0 + 8);
    uint4 vv0 = *(const uint4*)(vgp + koff0);
    uint4 vv1 = *(const uint4*)(vgp + koff0 + 8);

    for (int kt = kt0; kt < kt0 + 8; kt++){
        __syncthreads();                              // prev tile's LDS reads done
        *(uint4*)&Ks[kkey * LDK + kseg * 16]     = kv0;
        *(uint4*)&Ks[kkey * LDK + kseg * 16 + 8] = kv1;
        u16 vtmp[16];
        *(uint4*)&vtmp[0] = vv0;
        *(uint4*)&vtmp[8] = vv1;
        #pragma unroll
        for (int i = 0; i < 16; i++)
            Vt[(vdg * 16 + i) * LDK + vkey] = vtmp[i];   // 2 lanes/bank = free
        __syncthreads();

        if (kt < kt0 + 7){                            // issue next tile's loads under MFMA
            size_t koff = (size_t)(kt + 1) * 64 * 1536;
            kv0 = *(const uint4*)(kgp + koff);
            kv1 = *(const uint4*)(kgp + koff + 8);
            vv0 = *(const uint4*)(vgp + koff);
            vv1 = *(const uint4*)(vgp + koff + 8);
        }

        short8 kb[4][2];
        #pragma unroll
        for (int nb = 0; nb < 4; nb++){
            kb[nb][0] = *(const short8*)&Ks[(nb * 16 + mi) * LDK + quad * 8];
            kb[nb][1] = *(const short8*)&Ks[(nb * 16 + mi) * LDK + quad * 8 + 32];
        }
        #pragma unroll
        for (int qh = 0; qh < 2; qh++){
            #pragma unroll
            for (int nb = 0; nb < 4; nb++){
                f32x4 z = (f32x4){0.f, 0.f, 0.f, 0.f};
                __builtin_amdgcn_s_setprio(1);
                z = __builtin_amdgcn_mfma_f32_16x16x32_bf16(qf[qh][0], kb[nb][0], z, 0, 0, 0);
                z = __builtin_amdgcn_mfma_f32_16x16x32_bf16(qf[qh][1], kb[nb][1], z, 0, 0, 0);
                __builtin_amdgcn_s_setprio(0);
                float e0 = exp2f(fmaf(z[0], C1_LOG2E, -C2_LOG2E));
                float e1 = exp2f(fmaf(z[1], C1_LOG2E, -C2_LOG2E));
                float e2 = exp2f(fmaf(z[2], C1_LOG2E, -C2_LOG2E));
                float e3 = exp2f(fmaf(z[3], C1_LOG2E, -C2_LOG2E));
                u32 p01 = cvt_pk_bf16(e0, e1);
                u32 p23 = cvt_pk_bf16(e2, e3);
                u16* pp = &Ps[w][(qh * 16 + quad * 4) * LDK + nb * 16 + mi];
                pp[0]       = (u16)p01;
                pp[LDK]     = (u16)(p01 >> 16);
                pp[2 * LDK] = (u16)p23;
                pp[3 * LDK] = (u16)(p23 >> 16);
            }
        }
        short8 vb[4][2];
        #pragma unroll
        for (int nb = 0; nb < 4; nb++){
            vb[nb][0] = *(const short8*)&Vt[(nb * 16 + mi) * LDK + quad * 8];
            vb[nb][1] = *(const short8*)&Vt[(nb * 16 + mi) * LDK + quad * 8 + 32];
        }
        __builtin_amdgcn_s_setprio(1);
        #pragma unroll
        for (int qh = 0; qh < 2; qh++){
            const short8 a0 = *(const short8*)&Ps[w][(qh * 16 + mi) * LDK + quad * 8];
            const short8 a1 = *(const short8*)&Ps[w][(qh * 16 + mi) * LDK + quad * 8 + 32];
            #pragma unroll
            for (int nb = 0; nb < 4; nb++){
                o[qh][nb] = __builtin_amdgcn_mfma_f32_16x16x32_bf16(a0, vb[nb][0], o[qh][nb], 0, 0, 0);
                o[qh][nb] = __builtin_amdgcn_mfma_f32_16x16x32_bf16(a1, vb[nb][1], o[qh][nb], 0, 0, 0);
            }
            lacc[qh] = __builtin_amdgcn_mfma_f32_16x16x32_bf16(a0, ones, lacc[qh], 0, 0, 0);
            lacc[qh] = __builtin_amdgcn_mfma_f32_16x16x32_bf16(a1, ones, lacc[qh], 0, 0, 0);
        }
        __builtin_amdgcn_s_setprio(0);
    }
    u16* Ob = Opart + (size_t)sp * OSPLIT;
    float* lb2 = lpart + (size_t)sp * LSPLIT;
    #pragma unroll
    for (int qh = 0; qh < 2; qh++){
        int grow0 = b * 1024 + qt * 128 + w * 32 + qh * 16;
        u16* op = Ob + (size_t)grow0 * 512 + hoff;
        #pragma unroll
        for (int nb = 0; nb < 4; nb++){
            u32 c01 = cvt_pk_bf16(o[qh][nb][0], o[qh][nb][1]);
            u32 c23 = cvt_pk_bf16(o[qh][nb][2], o[qh][nb][3]);
            u16* cp = op + (size_t)(quad * 4) * 512 + nb * 16 + mi;
            cp[0]       = (u16)c01;
            cp[512]     = (u16)(c01 >> 16);
            cp[2 * 512] = (u16)c23;
            cp[3 * 512] = (u16)(c23 >> 16);
        }
        if (mi == 0){
            #pragma unroll
            for (int r = 0; r < 4; r++)
                lb2[(size_t)(grow0 + quad * 4 + r) * 8 + h] = lacc[qh][r];
        }
    }
}

// combine: out = bf16((O0+O1)/(l0+l1)); partials bf16; 8 elems/thread, fully coalesced
__global__ __launch_bounds__(256) void k_combine(const u16* __restrict__ Opart,
                                                 const float* __restrict__ lpart,
                                                 u16* __restrict__ out){
    int tid = blockIdx.x * 256 + threadIdx.x;
    size_t basei = (size_t)tid * 8;
    int row = (int)(basei >> 9), col = (int)(basei & 511), h = col >> 6;
    float l = lpart[(size_t)row * 8 + h] + lpart[(size_t)LSPLIT + (size_t)row * 8 + h];
    float inv = 1.f / l;
    uint4 a = *(const uint4*)(Opart + basei);
    uint4 bq = *(const uint4*)(Opart + (size_t)OSPLIT + basei);
    const u32* au = (const u32*)&a;
    const u32* bu = (const u32*)&bq;
    uint4 r;
    u32* ru = (u32*)&r;
    #pragma unroll
    for (int j = 0; j < 4; j++){
        float s0 = bf2f((u16)au[j])         + bf2f((u16)bu[j]);
        float s1 = bf2f((u16)(au[j] >> 16)) + bf2f((u16)(bu[j] >> 16));
        ru[j] = cvt_pk_bf16(s0 * inv, s1 * inv);
    }
    *(uint4*)(out + basei) = r;
}

// fallback single-pass flash, used when workspace too small for partials
__global__ __launch_bounds__(256) void k_flash(const u16* __restrict__ qkv, u16* __restrict__ out){
    __shared__ u16 Ks[64 * LDK];
    __shared__ u16 Vt[64 * LDK];
    __shared__ u16 Ps[4][32 * LDK];
    int wg = (blockIdx.x & 7) * 64 + (blockIdx.x >> 3);
    int qt = wg & 7, h = (wg >> 3) & 7, b = wg >> 6;
    int t = threadIdx.x;
    int w = t >> 6, lane = t & 63;
    int mi = lane & 15, quad = lane >> 4;

    const u16* base = qkv + ((size_t)b * 1024) * 1536;
    int hoff = h * 64;

    short8 ones;
    #pragma unroll
    for (int i = 0; i < 8; i++) ones[i] = (short)0x3F80;

    short8 qf[2][2];
    #pragma unroll
    for (int qh = 0; qh < 2; qh++){
        int qrow = qt * 128 + w * 32 + qh * 16 + mi;
        const u16* qp = base + (size_t)qrow * 1536 + hoff + quad * 8;
        qf[qh][0] = *(const short8*)(qp);
        qf[qh][1] = *(const short8*)(qp + 32);
    }
    f32x4 o[2][4];
    f32x4 lacc[2];
    #pragma unroll
    for (int qh = 0; qh < 2; qh++){
        #pragma unroll
        for (int nb = 0; nb < 4; nb++) o[qh][nb] = (f32x4){0.f, 0.f, 0.f, 0.f};
        lacc[qh] = (f32x4){0.f, 0.f, 0.f, 0.f};
    }
    int kkey = t >> 2, kseg = t & 3;
    const u16* kgp = base + (size_t)kkey * 1536 + 512 + hoff + kseg * 16;
    int vkey = lane, vdg = w;
    const u16* vgp = base + (size_t)vkey * 1536 + 1024 + hoff + vdg * 16;

    uint4 kv0 = *(const uint4*)(kgp);
    uint4 kv1 = *(const uint4*)(kgp + 8);
    uint4 vv0 = *(const uint4*)(vgp);
    uint4 vv1 = *(const uint4*)(vgp + 8);

    for (int kt = 0; kt < 16; kt++){
        __syncthreads();
        *(uint4*)&Ks[kkey * LDK + kseg * 16]     = kv0;
        *(uint4*)&Ks[kkey * LDK + kseg * 16 + 8] = kv1;
        u16 vtmp[16];
        *(uint4*)&vtmp[0] = vv0;
        *(uint4*)&vtmp[8] = vv1;
        #pragma unroll
        for (int i = 0; i < 16; i++)
            Vt[(vdg * 16 + i) * LDK + vkey] = vtmp[i];
        __syncthreads();
        if (kt < 15){
            size_t koff = (size_t)(kt + 1) * 64 * 1536;
            kv0 = *(const uint4*)(kgp + koff);
            kv1 = *(const uint4*)(kgp + koff + 8);
            vv0 = *(const uint4*)(vgp + koff);
            vv1 = *(const uint4*)(vgp + koff + 8);
        }
        short8 kb[4][2];
        #pragma unroll
        for (int nb = 0; nb < 4; nb++){
            kb[nb][0] = *(const short8*)&Ks[(nb * 16 + mi) * LDK + quad * 8];
            kb[nb][1] = *(const short8*)&Ks[(nb * 16 + mi) * LDK + quad * 8 + 32];
        }
        #pragma unroll
        for (int qh = 0; qh < 2; qh++){
            #pragma unroll
            for (int nb = 0; nb < 4; nb++){
                f32x4 z = (f32x4){0.f, 0.f, 0.f, 0.f};
                z = __builtin_amdgcn_mfma_f32_16x16x32_bf16(qf[qh][0], kb[nb][0], z, 0, 0, 0);
                z = __builtin_amdgcn_mfma_f32_16x16x32_bf16(qf[qh][1], kb[nb][1], z, 0, 0, 0);
                float e0 = exp2f(fmaf(z[0], C1_LOG2E, -C2_LOG2E));
                float e1 = exp2f(fmaf(z[1], C1_LOG2E, -C2_LOG2E));
                float e2 = exp2f(fmaf(z[2], C1_LOG2E, -C2_LOG2E));
                float e3 = exp2f(fmaf(z[3], C1_LOG2E, -C2_LOG2E));
                u32 p01 = cvt_pk_bf16(e0, e1);
                u32 p23 = cvt_pk_bf16(e2, e3);
                u16* pp = &Ps[w][(qh * 16 + quad * 4) * LDK + nb * 16 + mi];
                pp[0]       = (u16)p01;
                pp[LDK]     = (u16)(p01 >> 16);
                pp[2 * LDK] = (u16)p23;
                pp[3 * LDK] = (u16)(p23 >> 16);
            }
        }
        short8 vb[4][2];
        #pragma unroll
        for (int nb = 0; nb < 4; nb++){
            vb[nb][0] = *(const short8*)&Vt[(nb * 16 + mi) * LDK + quad * 8];
            vb[nb][1] = *(const short8*)&Vt[(nb * 16 + mi) * LDK + quad * 8 + 32];
        }
        #pragma unroll
        for (int qh = 0; qh < 2; qh++){
            const short8 a0 = *(const short8*)&Ps[w][(qh * 16 + mi) * LDK + quad * 8];
            const short8 a1 = *(const short8*)&Ps[w][(qh * 16 + mi) * LDK + quad * 8 + 32];
            #pragma unroll
            for (int nb = 0; nb < 4; nb++){
                o[qh][nb] = __builtin_amdgcn_mfma_f32_16x16x32_bf16(a0, vb[nb][0], o[qh][nb], 0, 0, 0);
                o[qh][nb] = __builtin_amdgcn_mfma_f32_16x16x32_bf16(a1, vb[nb][1], o[qh][nb], 0, 0, 0);
            }
            lacc[qh] = __builtin_amdgcn_mfma_f32_16x16x32_bf16(a0, ones, lacc[qh], 0, 0, 0);
            lacc[qh] = __builtin_amdgcn_mfma_f32_16x16x32_bf16(a1, ones, lacc[qh], 0, 0, 0);
        }
    }
    #pragma unroll
    for (int qh = 0; qh < 2; qh++){
        float invl[4];
        #pragma unroll
        for (int r = 0; r < 4; r++) invl[r] = 1.f / lacc[qh][r];
        u16* op = out + ((size_t)b * 1024 + qt * 128 + w * 32 + qh * 16) * 512 + hoff;
        #pragma unroll
        for (int nb = 0; nb < 4; nb++){
            u32 c01 = cvt_pk_bf16(o[qh][nb][0] * invl[0], o[qh][nb][1] * invl[1]);
            u32 c23 = cvt_pk_bf16(o[qh][nb][2] * invl[2], o[qh][nb][3] * invl[3]);
            u16* cp = op + (size_t)(quad * 4) * 512 + nb * 16 + mi;
            cp[0]       = (u16)c01;
            cp[512]     = (u16)(c01 >> 16);
            cp[2 * 512] = (u16)c23;
            cp[3 * 512] = (u16)(c23 >> 16);
        }
    }
}

// ---------------- host launch ----------------
extern "C" void kernel_launch(void* const* d_in, const int* in_sizes, int n_in,
                              void* d_out, int out_size, void* d_ws, size_t ws_size,
                              hipStream_t stream){
    const float* x_in  = (const float*)d_in[0];
    const float* ln1_s = (const float*)d_in[1];
    const float* ln1_b = (const float*)d_in[2];
    const float* w_qkv = (const float*)d_in[3];
    const float* w_out = (const float*)d_in[4];
    const float* b_out = (const float*)d_in[5];
    const float* ln2_s = (const float*)d_in[6];
    const float* ln2_b = (const float*)d_in[7];
    const float* w1    = (const float*)d_in[8];
    const float* b1    = (const float*)d_in[9];
    const float* w2    = (const float*)d_in[10];
    const float* b2    = (const float*)d_in[11];
    float* out = (float*)d_out;

    char* ws = (char*)d_ws;
    float* x_f32 = (float*)ws;   ws += (size_t)M_TOK * DIMM * 4;      // 16 MB fp32 residual
    u16* bufA    = (u16*)ws;     ws += (size_t)M_TOK * DIMM * 2;      // 8 MB  (ln_out / attn_out)
    u16* bufB    = (u16*)ws;     ws += (size_t)M_TOK * MLPD * 2;      // 32 MB (qkv / mlp_h)

    size_t per_layer_w = (size_t)(1536 + 512 + 2048 + 2048) * 512;    // u16 elems (6.3 MB)
    size_t split_bytes = (size_t)2 * OSPLIT * 2 + (size_t)2 * LSPLIT * 4;  // 17.3 MB (bf16 O)
    size_t base_used = (size_t)(ws - (char*)d_ws);

    bool split_ok = ws_size >= base_used + split_bytes + per_layer_w * 2;
    u16* Opart   = (u16*)ws;
    float* lpart = (float*)(ws + (size_t)2 * OSPLIT * 2);
    u16* wbase = split_ok ? (u16*)(ws + split_bytes) : (u16*)ws;
    size_t wb_off = (size_t)((char*)wbase - (char*)d_ws);
    bool big = ws_size >= wb_off + per_layer_w * 2 * DEPTH;

    u16* ln_out   = bufA;
    u16* attn_out = bufA;
    u16* qkv      = bufB;
    u16* mlp_h    = bufB;

    size_t x_bytes = (size_t)M_TOK * DIMM * sizeof(float);
    hipMemcpyAsync(x_f32, x_in, x_bytes, hipMemcpyDeviceToDevice, stream);

    const size_t off_qkv = 0;
    const size_t off_out = (size_t)1536 * 512;
    const size_t off_w1  = off_out + (size_t)512 * 512;
    const size_t off_w2  = off_w1 + (size_t)2048 * 512;

    if (big){
        k_transpose_cvt<<<dim3(48, 16, 6), dim3(32, 8), 0, stream>>>(w_qkv, wbase + off_qkv * DEPTH, 512, 1536);
        k_transpose_cvt<<<dim3(16, 16, 6), dim3(32, 8), 0, stream>>>(w_out, wbase + off_out * DEPTH, 512, 512);
        k_transpose_cvt<<<dim3(64, 16, 6), dim3(32, 8), 0, stream>>>(w1,    wbase + off_w1  * DEPTH, 512, 2048);
        k_transpose_cvt<<<dim3(16, 64, 6), dim3(32, 8), 0, stream>>>(w2,    wbase + off_w2  * DEPTH, 2048, 512);
    }

    for (int i = 0; i < DEPTH; i++){
        u16 *wqkvT, *woutT, *w1T, *w2T;
        if (big){
            wqkvT = wbase + off_qkv * DEPTH + (size_t)i * 1536 * 512;
            woutT = wbase + off_out * DEPTH + (size_t)i * 512 * 512;
            w1T   = wbase + off_w1  * DEPTH + (size_t)i * 2048 * 512;
            w2T   = wbase + off_w2  * DEPTH + (size_t)i * 512 * 2048;
        } else {
            wqkvT = wbase + off_qkv; woutT = wbase + off_out;
            w1T   = wbase + off_w1;  w2T   = wbase + off_w2;
            k_transpose_cvt<<<dim3(48, 16), dim3(32, 8), 0, stream>>>(w_qkv + (size_t)i * 512 * 1536, wqkvT, 512, 1536);
            k_transpose_cvt<<<dim3(16, 16), dim3(32, 8), 0, stream>>>(w_out + (size_t)i * 512 * 512,  woutT, 512, 512);
            k_transpose_cvt<<<dim3(64, 16), dim3(32, 8), 0, stream>>>(w1    + (size_t)i * 512 * 2048, w1T,   512, 2048);
            k_transpose_cvt<<<dim3(16, 64), dim3(32, 8), 0, stream>>>(w2    + (size_t)i * 2048 * 512, w2T,   2048, 512);
        }

        k_layernorm<<<dim3(M_TOK / 4), dim3(256), 0, stream>>>(x_f32, ln1_s + i * 512, ln1_b + i * 512, ln_out);
        k_gemm128b<0><<<dim3(12, 64), dim3(256), 0, stream>>>(ln_out, wqkvT, nullptr, qkv,
                                                              M_TOK, 1536, 512);
        if (split_ok){
            k_flash_split<<<dim3(1024), dim3(256), 0, stream>>>(qkv, Opart, lpart);
            k_combine<<<dim3(2048), dim3(256), 0, stream>>>(Opart, lpart, attn_out);
        } else {
            k_flash<<<dim3(512), dim3(256), 0, stream>>>(qkv, attn_out);
        }
        k_gemm128_res<<<dim3(4, 64), dim3(256), 0, stream>>>(attn_out, woutT, b_out + i * 512, x_f32,
                                                             M_TOK, 512, 512);
        k_layernorm<<<dim3(M_TOK / 4), dim3(256), 0, stream>>>(x_f32, ln2_s + i * 512, ln2_b + i * 512, ln_out);
        k_gemm128b<1><<<dim3(16, 64), dim3(256), 0, stream>>>(ln_out, w1T, b1 + i * 2048, mlp_h,
                                                              M_TOK, 2048, 512);
        k_gemm128_res<<<dim3(4, 64), dim3(256), 0, stream>>>(mlp_h, w2T, b2 + i * 512, x_f32,
                                                             M_TOK, 512, 2048);
    }
    hipMemcpyAsync(out, x_f32, x_bytes, hipMemcpyDeviceToDevice, stream);
}

// Round 8
// 1103.355 us; speedup vs baseline: 1.0141x; 1.0141x over previous
//
#include <hip/hip_runtime.h>
#include <cstdint>
#include <cstddef>

#define M_TOK 8192
#define DIMM  512
#define HEADS 8
#define DH    64
#define MLPD  2048
#define DEPTH 6

typedef unsigned short u16;
typedef unsigned int   u32;
typedef __attribute__((ext_vector_type(8))) short short8;   // 8 bf16 (4 VGPRs)
typedef __attribute__((ext_vector_type(4))) float f32x4;    // 4 fp32 acc

__device__ __forceinline__ float bf2f(u16 u){ return __uint_as_float(((u32)u) << 16); }
__device__ __forceinline__ u16 f2bf(float f){
    u32 x = __float_as_uint(f);
    u32 r = x + 0x7fffu + ((x >> 16) & 1u);   // RNE
    return (u16)(r >> 16);
}
// packed f32x2 -> bf16x2 (RNE), 1 instr for 2 converts
__device__ __forceinline__ u32 cvt_pk_bf16(float a, float b){
    u32 r;
    asm("v_cvt_pk_bf16_f32 %0, %1, %2" : "=v"(r) : "v"(a), "v"(b));
    return r;
}
// async global->LDS, 16B per lane; lds dest wave-uniform base (+lane*16 implicit); global addr per-lane
__device__ __forceinline__ void async16(const u16* g, u16* l){
    __builtin_amdgcn_global_load_lds(
        (const __attribute__((address_space(1))) void*)(uintptr_t)(const void*)g,
        (__attribute__((address_space(3))) void*)(u32)(uintptr_t)(void*)l,
        16, 0, 0);
}
// XCD-grouping block swizzle: put all x-blocks sharing an A-row-panel on one XCD.
__device__ __forceinline__ void xcd_swizzle(int& bx, int& by){
    int nbx = gridDim.x, nby = gridDim.y;
    if ((nby & 7) == 0){
        int i = by * nbx + bx;
        int xcd = i & 7, j = i >> 3, ypg = nby >> 3;
        int yq = j / nbx;
        by = xcd * ypg + yq;
        bx = j - yq * nbx;
    }
}

// ---------------- weight transpose + cvt: fp32 in[R][C] -> bf16 out[C][R], z layers ----------------
__global__ void k_transpose_cvt(const float* __restrict__ in, u16* __restrict__ out, int R, int C){
    __shared__ u16 tile[32][33];
    size_t zoff = (size_t)blockIdx.z * R * C;
    in += zoff; out += zoff;
    int c0 = blockIdx.x * 32, r0 = blockIdx.y * 32;
    int tx = threadIdx.x, ty = threadIdx.y;           // (32, 8)
    #pragma unroll
    for (int i = 0; i < 32; i += 8)
        tile[ty + i][tx] = f2bf(in[(size_t)(r0 + ty + i) * C + c0 + tx]);
    __syncthreads();
    #pragma unroll
    for (int i = 0; i < 32; i += 8)
        out[(size_t)(c0 + ty + i) * R + r0 + tx] = tile[tx][ty + i];
}

// ---------------- LayerNorm: fp32 x row -> bf16 out; 4 rows/block, 1 wave/row ----------------
__global__ __launch_bounds__(256) void k_layernorm(const float* __restrict__ x,
                                                   const float* __restrict__ s,
                                                   const float* __restrict__ b,
                                                   u16* __restrict__ out){
    int row = blockIdx.x * 4 + (threadIdx.x >> 6);
    int lane = threadIdx.x & 63;
    const float* xp = x + (size_t)row * DIMM + lane * 8;
    float v[8];
    #pragma unroll
    for (int c = 0; c < 8; c++) v[c] = xp[c];
    float sum = 0.f, sq = 0.f;
    #pragma unroll
    for (int c = 0; c < 8; c++){ sum += v[c]; sq += v[c] * v[c]; }
    #pragma unroll
    for (int m = 32; m >= 1; m >>= 1){
        sum += __shfl_xor(sum, m);
        sq  += __shfl_xor(sq,  m);
    }
    float mu  = sum * (1.f / DIMM);
    float var = sq * (1.f / DIMM) - mu * mu;
    float rs  = rsqrtf(var + 1e-5f);
    u16* op = out + (size_t)row * DIMM + lane * 8;
    #pragma unroll
    for (int c = 0; c < 8; c++){
        int col = lane * 8 + c;
        op[c] = f2bf((v[c] - mu) * rs * s[col] + b[col]);
    }
}

// Abramowitz-Stegun 7.1.26 erf (abs err 1.5e-7): rcp + 5 FMA + exp2, no branches.
__device__ __forceinline__ float erf_as(float x){
    float ax = fabsf(x);
    float t  = __builtin_amdgcn_rcpf(fmaf(0.3275911f, ax, 1.f));
    float y  = fmaf(fmaf(fmaf(fmaf(1.061405429f, t, -1.453152027f), t,
                              1.421413741f), t, -0.284496736f), t, 0.254829592f) * t;
    float e  = exp2f(-ax * ax * 1.4426950408889634f);
    float r  = 1.f - y * e;
    return copysignf(r, x);
}
__device__ __forceinline__ float gelu_exact(float v){
    return 0.5f * v * (1.f + erf_as(v * 0.70710678118654752f));
}

#define LDT64 72   // padded stride for epilogue LDS scratch only

// ============ 128x128-tile GEMM, BK=64, dbuf + counted-vmcnt raw-barrier pipeline + T2 swizzle ========
// (unchanged from round 6 — verified)
template<int MODE>
__global__ __launch_bounds__(256) void k_gemm128b(const u16* __restrict__ A,
                                                  const u16* __restrict__ Bt,
                                                  const float* __restrict__ bias,
                                                  u16* __restrict__ Cout,
                                                  int M, int N, int K){
    __shared__ u16 As[2][128 * 64];
    __shared__ u16 Bs[2][128 * 64];
    int bx = blockIdx.x, by = blockIdx.y;
    xcd_swizzle(bx, by);
    int m0 = by * 128, n0 = bx * 128;
    int t = threadIdx.x;
    int w = t >> 6, lane = t & 63;
    int mi = lane & 15, quad = lane >> 4;
    int wr = w >> 1, wc = w & 1;
    int sw = mi & 7;                      // read-side XOR key (row&7 == mi&7 for fragment rows)

    int grow = lane >> 3;
    int gcol = (((lane & 7) ^ grow) & 7) * 8;
    const u16* agl = A  + (size_t)(m0 + w * 32 + grow) * K + gcol;
    const u16* bgl = Bt + (size_t)(n0 + w * 32 + grow) * K + gcol;

    f32x4 acc[4][4];
    #pragma unroll
    for (int mt = 0; mt < 4; mt++)
        #pragma unroll
        for (int nt = 0; nt < 4; nt++) acc[mt][nt] = (f32x4){0.f, 0.f, 0.f, 0.f};

    int nt_k = K >> 6;
    {   // prologue: stage tile 0 -> buf 0 (8 loads/wave in flight)
        u16* asl = &As[0][(w * 32) * 64];
        u16* bsl = &Bs[0][(w * 32) * 64];
        #pragma unroll
        for (int i = 0; i < 4; i++){
            async16(agl + (size_t)(i * 8) * K, asl + i * 8 * 64);
            async16(bgl + (size_t)(i * 8) * K, bsl + i * 8 * 64);
        }
    }

    for (int td = 0; td < nt_k; td++){
        int cur = td & 1;
        if (td + 1 < nt_k){                    // stage next tile, then wait ONLY for tile td
            int k0 = (td + 1) << 6;
            u16* asl = &As[cur ^ 1][(w * 32) * 64];
            u16* bsl = &Bs[cur ^ 1][(w * 32) * 64];
            #pragma unroll
            for (int i = 0; i < 4; i++){
                async16(agl + (size_t)(i * 8) * K + k0, asl + i * 8 * 64);
                async16(bgl + (size_t)(i * 8) * K + k0, bsl + i * 8 * 64);
            }
            asm volatile("s_waitcnt vmcnt(8)" ::: "memory");
        } else {
            asm volatile("s_waitcnt vmcnt(0)" ::: "memory");
        }
        __builtin_amdgcn_s_barrier();          // all waves' tile-td loads landed
        __builtin_amdgcn_sched_barrier(0);
        const u16* Ab = &As[cur][0];
        const u16* Bb = &Bs[cur][0];
        #pragma unroll
        for (int kk = 0; kk < 64; kk += 32){
            const int kc = kk >> 3;            // logical chunk base: 0 or 4
            short8 af[4], bf[4];
            #pragma unroll
            for (int mt = 0; mt < 4; mt++)
                af[mt] = *(const short8*)&Ab[(wr * 64 + mt * 16 + mi) * 64 + (((quad + kc) ^ sw) * 8)];
            #pragma unroll
            for (int nt = 0; nt < 4; nt++)
                bf[nt] = *(const short8*)&Bb[(wc * 64 + nt * 16 + mi) * 64 + (((quad + kc) ^ sw) * 8)];
            #pragma unroll
            for (int mt = 0; mt < 4; mt++)
                #pragma unroll
                for (int nt = 0; nt < 4; nt++)
                    acc[mt][nt] = __builtin_amdgcn_mfma_f32_16x16x32_bf16(af[mt], bf[nt], acc[mt][nt], 0, 0, 0);
        }
        __builtin_amdgcn_sched_barrier(0);
        __builtin_amdgcn_s_barrier();          // all reads of buf[cur] done -> safe to overwrite next iter
    }

    // ---- coalesced epilogue: per-wave C-subtile through LDS (wave-private scratch over As) ----
    float bv[4];
    if (MODE == 1){
        #pragma unroll
        for (int nt = 0; nt < 4; nt++) bv[nt] = bias[n0 + wc * 64 + nt * 16 + mi];
    }
    u16* cs = ((u16*)As) + w * 16 * LDT64;     // 16x72 u16 per wave
    int erow = lane >> 2, ecol = (lane & 3) * 16;
    #pragma unroll
    for (int mt = 0; mt < 4; mt++){
        #pragma unroll
        for (int nt = 0; nt < 4; nt++)
            #pragma unroll
            for (int r = 0; r < 4; r++){
                float v = acc[mt][nt][r];
                if (MODE == 1) v = gelu_exact(v + bv[nt]);
                cs[(quad * 4 + r) * LDT64 + nt * 16 + mi] = f2bf(v);
            }
        uint4 c0 = *(const uint4*)&cs[erow * LDT64 + ecol];
        uint4 c1 = *(const uint4*)&cs[erow * LDT64 + ecol + 8];
        u16* cp = Cout + (size_t)(m0 + wr * 64 + mt * 16 + erow) * N + n0 + wc * 64 + ecol;
        *(uint4*)cp       = c0;
        *(uint4*)(cp + 8) = c1;
    }
}

// ============ 128x128-tile GEMM, same pipeline+swizzle, fp32 residual RMW epilogue (unchanged) ========
__global__ __launch_bounds__(256) void k_gemm128_res(const u16* __restrict__ A,
                                                     const u16* __restrict__ Bt,
                                                     const float* __restrict__ bias,
                                                     float* __restrict__ xres,
                                                     int M, int N, int K){
    __shared__ u16 As[2][128 * 64];
    __shared__ u16 Bs[2][128 * 64];
    int bx = blockIdx.x, by = blockIdx.y;
    xcd_swizzle(bx, by);
    int m0 = by * 128, n0 = bx * 128;
    int t = threadIdx.x;
    int w = t >> 6, lane = t & 63;
    int mi = lane & 15, quad = lane >> 4;
    int wr = w >> 1, wc = w & 1;
    int sw = mi & 7;

    int grow = lane >> 3;
    int gcol = (((lane & 7) ^ grow) & 7) * 8;
    const u16* agl = A  + (size_t)(m0 + w * 32 + grow) * K + gcol;
    const u16* bgl = Bt + (size_t)(n0 + w * 32 + grow) * K + gcol;

    f32x4 acc[4][4];
    #pragma unroll
    for (int mt = 0; mt < 4; mt++)
        #pragma unroll
        for (int nt = 0; nt < 4; nt++) acc[mt][nt] = (f32x4){0.f, 0.f, 0.f, 0.f};

    int nt_k = K >> 6;
    {   // prologue
        u16* asl = &As[0][(w * 32) * 64];
        u16* bsl = &Bs[0][(w * 32) * 64];
        #pragma unroll
        for (int i = 0; i < 4; i++){
            async16(agl + (size_t)(i * 8) * K, asl + i * 8 * 64);
            async16(bgl + (size_t)(i * 8) * K, bsl + i * 8 * 64);
        }
    }

    for (int td = 0; td < nt_k; td++){
        int cur = td & 1;
        if (td + 1 < nt_k){
            int k0 = (td + 1) << 6;
            u16* asl = &As[cur ^ 1][(w * 32) * 64];
            u16* bsl = &Bs[cur ^ 1][(w * 32) * 64];
            #pragma unroll
            for (int i = 0; i < 4; i++){
                async16(agl + (size_t)(i * 8) * K + k0, asl + i * 8 * 64);
                async16(bgl + (size_t)(i * 8) * K + k0, bsl + i * 8 * 64);
            }
            asm volatile("s_waitcnt vmcnt(8)" ::: "memory");
        } else {
            asm volatile("s_waitcnt vmcnt(0)" ::: "memory");
        }
        __builtin_amdgcn_s_barrier();
        __builtin_amdgcn_sched_barrier(0);
        const u16* Ab = &As[cur][0];
        const u16* Bb = &Bs[cur][0];
        #pragma unroll
        for (int kk = 0; kk < 64; kk += 32){
            const int kc = kk >> 3;
            short8 af[4], bf[4];
            #pragma unroll
            for (int mt = 0; mt < 4; mt++)
                af[mt] = *(const short8*)&Ab[(wr * 64 + mt * 16 + mi) * 64 + (((quad + kc) ^ sw) * 8)];
            #pragma unroll
            for (int nt = 0; nt < 4; nt++)
                bf[nt] = *(const short8*)&Bb[(wc * 64 + nt * 16 + mi) * 64 + (((quad + kc) ^ sw) * 8)];
            #pragma unroll
            for (int mt = 0; mt < 4; mt++)
                #pragma unroll
                for (int nt = 0; nt < 4; nt++)
                    acc[mt][nt] = __builtin_amdgcn_mfma_f32_16x16x32_bf16(af[mt], bf[nt], acc[mt][nt], 0, 0, 0);
        }
        __builtin_amdgcn_sched_barrier(0);
        __builtin_amdgcn_s_barrier();
    }

    // ---- coalesced fp32 RMW epilogue through LDS (per-wave 16x72 fp32 region over As) ----
    float bv[4];
    #pragma unroll
    for (int nt = 0; nt < 4; nt++) bv[nt] = bias[n0 + wc * 64 + nt * 16 + mi];
    float* cs = ((float*)As) + w * 16 * LDT64;
    int erow = lane >> 2, ecol = (lane & 3) * 16;
    #pragma unroll
    for (int mt = 0; mt < 4; mt++){
        #pragma unroll
        for (int nt = 0; nt < 4; nt++)
            #pragma unroll
            for (int r = 0; r < 4; r++)
                cs[(quad * 4 + r) * LDT64 + nt * 16 + mi] = acc[mt][nt][r] + bv[nt];
        float* xp = xres + (size_t)(m0 + wr * 64 + mt * 16 + erow) * N + n0 + wc * 64 + ecol;
        #pragma unroll
        for (int j = 0; j < 4; j++){
            float4 cv = *(const float4*)&cs[erow * LDT64 + ecol + j * 4];
            float4 xv = *(const float4*)(xp + j * 4);
            xv.x += cv.x; xv.y += cv.y; xv.z += cv.z; xv.w += cv.w;
            *(float4*)(xp + j * 4) = xv;
        }
    }
}

// ---------------- MFMA flash attention ----------------
#define LDK 72
#define LDP 40                          // Ps chunk stride: 32 keys + 8 pad (16B-aligned rows)
#define C1_LOG2E 0.18033688011112042f   // 0.125 * log2(e)
#define C2_LOG2E 11.541560327111707f    // 8 * log2(e)
#define OSPLIT (M_TOK * 512)            // elems per split O buffer (bf16)
#define LSPLIT (M_TOK * 8)              // floats per split l buffer

// split-K flash: grid 1024 (2 splits x 512); fixed-max softmax => partials combine exactly.
// v3: PV chunked into two 32-key halves -> Ps shrinks 18.4K -> 10.2K; LDS 28.7K -> 5 blocks/CU.
// Ps is wave-private (in-wave DS ordering covers write->read; no extra barriers).
__global__ __launch_bounds__(256) void k_flash_split(const u16* __restrict__ qkv,
                                                     u16* __restrict__ Opart,
                                                     float* __restrict__ lpart){
    __shared__ u16 Ks[64 * LDK];        // [key][dim]
    __shared__ u16 Vt[64 * LDK];        // [dim][key]
    __shared__ u16 Ps[4][32 * LDP];     // per-wave P chunk [q32][32 keys]
    // XCD swizzle: nwg=1024, cpx=128 -> XCD k owns batch k (both splits co-located)
    int wg = (blockIdx.x & 7) * 128 + (blockIdx.x >> 3);
    int qt = wg & 7, h = (wg >> 3) & 7, sp = (wg >> 6) & 1, b = wg >> 7;
    int t = threadIdx.x;
    int w = t >> 6, lane = t & 63;
    int mi = lane & 15, quad = lane >> 4;

    const u16* base = qkv + ((size_t)b * 1024) * 1536;
    int hoff = h * 64;

    short8 ones;
    #pragma unroll
    for (int i = 0; i < 8; i++) ones[i] = (short)0x3F80;   // bf16 1.0

    short8 qf[2][2];
    #pragma unroll
    for (int qh = 0; qh < 2; qh++){
        int qrow = qt * 128 + w * 32 + qh * 16 + mi;
        const u16* qp = base + (size_t)qrow * 1536 + hoff + quad * 8;
        qf[qh][0] = *(const short8*)(qp);
        qf[qh][1] = *(const short8*)(qp + 32);
    }

    f32x4 o[2][4];
    f32x4 lacc[2];
    #pragma unroll
    for (int qh = 0; qh < 2; qh++){
        #pragma unroll
        for (int nb = 0; nb < 4; nb++) o[qh][nb] = (f32x4){0.f, 0.f, 0.f, 0.f};
        lacc[qh] = (f32x4){0.f, 0.f, 0.f, 0.f};
    }

    int kkey = t >> 2, kseg = t & 3;
    const u16* kgp = base + (size_t)kkey * 1536 + 512 + hoff + kseg * 16;
    int vkey = lane, vdg = w;
    const u16* vgp = base + (size_t)vkey * 1536 + 1024 + hoff + vdg * 16;

    int kt0 = sp * 8;
    size_t koff0 = (size_t)kt0 * 64 * 1536;
    uint4 kv0 = *(const uint4*)(kgp + koff0);
    uint4 kv1 = *(const uint4*)(kgp + koff0 + 8);
    uint4 vv0 = *(const uint4*)(vgp + koff0);
    uint4 vv1 = *(const uint4*)(vgp + koff0 + 8);

    for (int kt = kt0; kt < kt0 + 8; kt++){
        __syncthreads();                              // prev tile's LDS reads done
        *(uint4*)&Ks[kkey * LDK + kseg * 16]     = kv0;
        *(uint4*)&Ks[kkey * LDK + kseg * 16 + 8] = kv1;
        u16 vtmp[16];
        *(uint4*)&vtmp[0] = vv0;
        *(uint4*)&vtmp[8] = vv1;
        #pragma unroll
        for (int i = 0; i < 16; i++)
            Vt[(vdg * 16 + i) * LDK + vkey] = vtmp[i];   // 2 lanes/bank = free
        __syncthreads();

        if (kt < kt0 + 7){                            // issue next tile's loads under MFMA
            size_t koff = (size_t)(kt + 1) * 64 * 1536;
            kv0 = *(const uint4*)(kgp + koff);
            kv1 = *(const uint4*)(kgp + koff + 8);
            vv0 = *(const uint4*)(vgp + koff);
            vv1 = *(const uint4*)(vgp + koff + 8);
        }

        // ---- two 32-key chunks: QK -> P chunk -> partial PV ----
        #pragma unroll
        for (int kh = 0; kh < 2; kh++){
            // K fragments for this chunk's 2 key-blocks
            short8 kb[2][2];
            #pragma unroll
            for (int nbl = 0; nbl < 2; nbl++){
                int nb = kh * 2 + nbl;
                kb[nbl][0] = *(const short8*)&Ks[(nb * 16 + mi) * LDK + quad * 8];
                kb[nbl][1] = *(const short8*)&Ks[(nb * 16 + mi) * LDK + quad * 8 + 32];
            }
            // S = Q K^T, P = exp2(S*c1 - c2) -> Ps chunk
            #pragma unroll
            for (int qh = 0; qh < 2; qh++){
                #pragma unroll
                for (int nbl = 0; nbl < 2; nbl++){
                    f32x4 z = (f32x4){0.f, 0.f, 0.f, 0.f};
                    z = __builtin_amdgcn_mfma_f32_16x16x32_bf16(qf[qh][0], kb[nbl][0], z, 0, 0, 0);
                    z = __builtin_amdgcn_mfma_f32_16x16x32_bf16(qf[qh][1], kb[nbl][1], z, 0, 0, 0);
                    float e0 = exp2f(fmaf(z[0], C1_LOG2E, -C2_LOG2E));
                    float e1 = exp2f(fmaf(z[1], C1_LOG2E, -C2_LOG2E));
                    float e2 = exp2f(fmaf(z[2], C1_LOG2E, -C2_LOG2E));
                    float e3 = exp2f(fmaf(z[3], C1_LOG2E, -C2_LOG2E));
                    u32 p01 = cvt_pk_bf16(e0, e1);
                    u32 p23 = cvt_pk_bf16(e2, e3);
                    u16* pp = &Ps[w][(qh * 16 + quad * 4) * LDP + nbl * 16 + mi];
                    pp[0]       = (u16)p01;
                    pp[LDP]     = (u16)(p01 >> 16);
                    pp[2 * LDP] = (u16)p23;
                    pp[3 * LDP] = (u16)(p23 >> 16);
                }
            }
            // V fragments for this chunk (keys kh*32..+31, all 4 dim-blocks)
            short8 vb[4];
            #pragma unroll
            for (int nb = 0; nb < 4; nb++)
                vb[nb] = *(const short8*)&Vt[(nb * 16 + mi) * LDK + kh * 32 + quad * 8];
            // partial PV + l (wave-private Ps: in-wave DS ordering, no barrier)
            #pragma unroll
            for (int qh = 0; qh < 2; qh++){
                const short8 a = *(const short8*)&Ps[w][(qh * 16 + mi) * LDP + quad * 8];
                #pragma unroll
                for (int nb = 0; nb < 4; nb++)
                    o[qh][nb] = __builtin_amdgcn_mfma_f32_16x16x32_bf16(a, vb[nb], o[qh][nb], 0, 0, 0);
                lacc[qh] = __builtin_amdgcn_mfma_f32_16x16x32_bf16(a, ones, lacc[qh], 0, 0, 0);
            }
        }
    }
    u16* Ob = Opart + (size_t)sp * OSPLIT;
    float* lb2 = lpart + (size_t)sp * LSPLIT;
    #pragma unroll
    for (int qh = 0; qh < 2; qh++){
        int grow0 = b * 1024 + qt * 128 + w * 32 + qh * 16;
        u16* op = Ob + (size_t)grow0 * 512 + hoff;
        #pragma unroll
        for (int nb = 0; nb < 4; nb++){
            u32 c01 = cvt_pk_bf16(o[qh][nb][0], o[qh][nb][1]);
            u32 c23 = cvt_pk_bf16(o[qh][nb][2], o[qh][nb][3]);
            u16* cp = op + (size_t)(quad * 4) * 512 + nb * 16 + mi;
            cp[0]       = (u16)c01;
            cp[512]     = (u16)(c01 >> 16);
            cp[2 * 512] = (u16)c23;
            cp[3 * 512] = (u16)(c23 >> 16);
        }
        if (mi == 0){
            #pragma unroll
            for (int r = 0; r < 4; r++)
                lb2[(size_t)(grow0 + quad * 4 + r) * 8 + h] = lacc[qh][r];
        }
    }
}

// combine: out = bf16((O0+O1)/(l0+l1)); partials bf16; 8 elems/thread, fully coalesced
__global__ __launch_bounds__(256) void k_combine(const u16* __restrict__ Opart,
                                                 const float* __restrict__ lpart,
                                                 u16* __restrict__ out){
    int tid = blockIdx.x * 256 + threadIdx.x;
    size_t basei = (size_t)tid * 8;
    int row = (int)(basei >> 9), col = (int)(basei & 511), h = col >> 6;
    float l = lpart[(size_t)row * 8 + h] + lpart[(size_t)LSPLIT + (size_t)row * 8 + h];
    float inv = 1.f / l;
    uint4 a = *(const uint4*)(Opart + basei);
    uint4 bq = *(const uint4*)(Opart + (size_t)OSPLIT + basei);
    const u32* au = (const u32*)&a;
    const u32* bu = (const u32*)&bq;
    uint4 r;
    u32* ru = (u32*)&r;
    #pragma unroll
    for (int j = 0; j < 4; j++){
        float s0 = bf2f((u16)au[j])         + bf2f((u16)bu[j]);
        float s1 = bf2f((u16)(au[j] >> 16)) + bf2f((u16)(bu[j] >> 16));
        ru[j] = cvt_pk_bf16(s0 * inv, s1 * inv);
    }
    *(uint4*)(out + basei) = r;
}

// fallback single-pass flash, used when workspace too small for partials
__global__ __launch_bounds__(256) void k_flash(const u16* __restrict__ qkv, u16* __restrict__ out){
    __shared__ u16 Ks[64 * LDK];
    __shared__ u16 Vt[64 * LDK];
    __shared__ u16 Ps[4][32 * LDK];
    int wg = (blockIdx.x & 7) * 64 + (blockIdx.x >> 3);
    int qt = wg & 7, h = (wg >> 3) & 7, b = wg >> 6;
    int t = threadIdx.x;
    int w = t >> 6, lane = t & 63;
    int mi = lane & 15, quad = lane >> 4;

    const u16* base = qkv + ((size_t)b * 1024) * 1536;
    int hoff = h * 64;

    short8 ones;
    #pragma unroll
    for (int i = 0; i < 8; i++) ones[i] = (short)0x3F80;

    short8 qf[2][2];
    #pragma unroll
    for (int qh = 0; qh < 2; qh++){
        int qrow = qt * 128 + w * 32 + qh * 16 + mi;
        const u16* qp = base + (size_t)qrow * 1536 + hoff + quad * 8;
        qf[qh][0] = *(const short8*)(qp);
        qf[qh][1] = *(const short8*)(qp + 32);
    }
    f32x4 o[2][4];
    f32x4 lacc[2];
    #pragma unroll
    for (int qh = 0; qh < 2; qh++){
        #pragma unroll
        for (int nb = 0; nb < 4; nb++) o[qh][nb] = (f32x4){0.f, 0.f, 0.f, 0.f};
        lacc[qh] = (f32x4){0.f, 0.f, 0.f, 0.f};
    }
    int kkey = t >> 2, kseg = t & 3;
    const u16* kgp = base + (size_t)kkey * 1536 + 512 + hoff + kseg * 16;
    int vkey = lane, vdg = w;
    const u16* vgp = base + (size_t)vkey * 1536 + 1024 + hoff + vdg * 16;

    uint4 kv0 = *(const uint4*)(kgp);
    uint4 kv1 = *(const uint4*)(kgp + 8);
    uint4 vv0 = *(const uint4*)(vgp);
    uint4 vv1 = *(const uint4*)(vgp + 8);

    for (int kt = 0; kt < 16; kt++){
        __syncthreads();
        *(uint4*)&Ks[kkey * LDK + kseg * 16]     = kv0;
        *(uint4*)&Ks[kkey * LDK + kseg * 16 + 8] = kv1;
        u16 vtmp[16];
        *(uint4*)&vtmp[0] = vv0;
        *(uint4*)&vtmp[8] = vv1;
        #pragma unroll
        for (int i = 0; i < 16; i++)
            Vt[(vdg * 16 + i) * LDK + vkey] = vtmp[i];
        __syncthreads();
        if (kt < 15){
            size_t koff = (size_t)(kt + 1) * 64 * 1536;
            kv0 = *(const uint4*)(kgp + koff);
            kv1 = *(const uint4*)(kgp + koff + 8);
            vv0 = *(const uint4*)(vgp + koff);
            vv1 = *(const uint4*)(vgp + koff + 8);
        }
        short8 kb[4][2];
        #pragma unroll
        for (int nb = 0; nb < 4; nb++){
            kb[nb][0] = *(const short8*)&Ks[(nb * 16 + mi) * LDK + quad * 8];
            kb[nb][1] = *(const short8*)&Ks[(nb * 16 + mi) * LDK + quad * 8 + 32];
        }
        #pragma unroll
        for (int qh = 0; qh < 2; qh++){
            #pragma unroll
            for (int nb = 0; nb < 4; nb++){
                f32x4 z = (f32x4){0.f, 0.f, 0.f, 0.f};
                z = __builtin_amdgcn_mfma_f32_16x16x32_bf16(qf[qh][0], kb[nb][0], z, 0, 0, 0);
                z = __builtin_amdgcn_mfma_f32_16x16x32_bf16(qf[qh][1], kb[nb][1], z, 0, 0, 0);
                float e0 = exp2f(fmaf(z[0], C1_LOG2E, -C2_LOG2E));
                float e1 = exp2f(fmaf(z[1], C1_LOG2E, -C2_LOG2E));
                float e2 = exp2f(fmaf(z[2], C1_LOG2E, -C2_LOG2E));
                float e3 = exp2f(fmaf(z[3], C1_LOG2E, -C2_LOG2E));
                u32 p01 = cvt_pk_bf16(e0, e1);
                u32 p23 = cvt_pk_bf16(e2, e3);
                u16* pp = &Ps[w][(qh * 16 + quad * 4) * LDK + nb * 16 + mi];
                pp[0]       = (u16)p01;
                pp[LDK]     = (u16)(p01 >> 16);
                pp[2 * LDK] = (u16)p23;
                pp[3 * LDK] = (u16)(p23 >> 16);
            }
        }
        short8 vb[4][2];
        #pragma unroll
        for (int nb = 0; nb < 4; nb++){
            vb[nb][0] = *(const short8*)&Vt[(nb * 16 + mi) * LDK + quad * 8];
            vb[nb][1] = *(const short8*)&Vt[(nb * 16 + mi) * LDK + quad * 8 + 32];
        }
        #pragma unroll
        for (int qh = 0; qh < 2; qh++){
            const short8 a0 = *(const short8*)&Ps[w][(qh * 16 + mi) * LDK + quad * 8];
            const short8 a1 = *(const short8*)&Ps[w][(qh * 16 + mi) * LDK + quad * 8 + 32];
            #pragma unroll
            for (int nb = 0; nb < 4; nb++){
                o[qh][nb] = __builtin_amdgcn_mfma_f32_16x16x32_bf16(a0, vb[nb][0], o[qh][nb], 0, 0, 0);
                o[qh][nb] = __builtin_amdgcn_mfma_f32_16x16x32_bf16(a1, vb[nb][1], o[qh][nb], 0, 0, 0);
            }
            lacc[qh] = __builtin_amdgcn_mfma_f32_16x16x32_bf16(a0, ones, lacc[qh], 0, 0, 0);
            lacc[qh] = __builtin_amdgcn_mfma_f32_16x16x32_bf16(a1, ones, lacc[qh], 0, 0, 0);
        }
    }
    #pragma unroll
    for (int qh = 0; qh < 2; qh++){
        float invl[4];
        #pragma unroll
        for (int r = 0; r < 4; r++) invl[r] = 1.f / lacc[qh][r];
        u16* op = out + ((size_t)b * 1024 + qt * 128 + w * 32 + qh * 16) * 512 + hoff;
        #pragma unroll
        for (int nb = 0; nb < 4; nb++){
            u32 c01 = cvt_pk_bf16(o[qh][nb][0] * invl[0], o[qh][nb][1] * invl[1]);
            u32 c23 = cvt_pk_bf16(o[qh][nb][2] * invl[2], o[qh][nb][3] * invl[3]);
            u16* cp = op + (size_t)(quad * 4) * 512 + nb * 16 + mi;
            cp[0]       = (u16)c01;
            cp[512]     = (u16)(c01 >> 16);
            cp[2 * 512] = (u16)c23;
            cp[3 * 512] = (u16)(c23 >> 16);
        }
    }
}

// ---------------- host launch ----------------
extern "C" void kernel_launch(void* const* d_in, const int* in_sizes, int n_in,
                              void* d_out, int out_size, void* d_ws, size_t ws_size,
                              hipStream_t stream){
    const float* x_in  = (const float*)d_in[0];
    const float* ln1_s = (const float*)d_in[1];
    const float* ln1_b = (const float*)d_in[2];
    const float* w_qkv = (const float*)d_in[3];
    const float* w_out = (const float*)d_in[4];
    const float* b_out = (const float*)d_in[5];
    const float* ln2_s = (const float*)d_in[6];
    const float* ln2_b = (const float*)d_in[7];
    const float* w1    = (const float*)d_in[8];
    const float* b1    = (const float*)d_in[9];
    const float* w2    = (const float*)d_in[10];
    const float* b2    = (const float*)d_in[11];
    float* out = (float*)d_out;

    char* ws = (char*)d_ws;
    float* x_f32 = (float*)ws;   ws += (size_t)M_TOK * DIMM * 4;      // 16 MB fp32 residual
    u16* bufA    = (u16*)ws;     ws += (size_t)M_TOK * DIMM * 2;      // 8 MB  (ln_out / attn_out)
    u16* bufB    = (u16*)ws;     ws += (size_t)M_TOK * MLPD * 2;      // 32 MB (qkv / mlp_h)

    size_t per_layer_w = (size_t)(1536 + 512 + 2048 + 2048) * 512;    // u16 elems (6.3 MB)
    size_t split_bytes = (size_t)2 * OSPLIT * 2 + (size_t)2 * LSPLIT * 4;  // 17.3 MB (bf16 O)
    size_t base_used = (size_t)(ws - (char*)d_ws);

    bool split_ok = ws_size >= base_used + split_bytes + per_layer_w * 2;
    u16* Opart   = (u16*)ws;
    float* lpart = (float*)(ws + (size_t)2 * OSPLIT * 2);
    u16* wbase = split_ok ? (u16*)(ws + split_bytes) : (u16*)ws;
    size_t wb_off = (size_t)((char*)wbase - (char*)d_ws);
    bool big = ws_size >= wb_off + per_layer_w * 2 * DEPTH;

    u16* ln_out   = bufA;
    u16* attn_out = bufA;
    u16* qkv      = bufB;
    u16* mlp_h    = bufB;

    size_t x_bytes = (size_t)M_TOK * DIMM * sizeof(float);
    hipMemcpyAsync(x_f32, x_in, x_bytes, hipMemcpyDeviceToDevice, stream);

    const size_t off_qkv = 0;
    const size_t off_out = (size_t)1536 * 512;
    const size_t off_w1  = off_out + (size_t)512 * 512;
    const size_t off_w2  = off_w1 + (size_t)2048 * 512;

    if (big){
        k_transpose_cvt<<<dim3(48, 16, 6), dim3(32, 8), 0, stream>>>(w_qkv, wbase + off_qkv * DEPTH, 512, 1536);
        k_transpose_cvt<<<dim3(16, 16, 6), dim3(32, 8), 0, stream>>>(w_out, wbase + off_out * DEPTH, 512, 512);
        k_transpose_cvt<<<dim3(64, 16, 6), dim3(32, 8), 0, stream>>>(w1,    wbase + off_w1  * DEPTH, 512, 2048);
        k_transpose_cvt<<<dim3(16, 64, 6), dim3(32, 8), 0, stream>>>(w2,    wbase + off_w2  * DEPTH, 2048, 512);
    }

    for (int i = 0; i < DEPTH; i++){
        u16 *wqkvT, *woutT, *w1T, *w2T;
        if (big){
            wqkvT = wbase + off_qkv * DEPTH + (size_t)i * 1536 * 512;
            woutT = wbase + off_out * DEPTH + (size_t)i * 512 * 512;
            w1T   = wbase + off_w1  * DEPTH + (size_t)i * 2048 * 512;
            w2T   = wbase + off_w2  * DEPTH + (size_t)i * 512 * 2048;
        } else {
            wqkvT = wbase + off_qkv; woutT = wbase + off_out;
            w1T   = wbase + off_w1;  w2T   = wbase + off_w2;
            k_transpose_cvt<<<dim3(48, 16), dim3(32, 8), 0, stream>>>(w_qkv + (size_t)i * 512 * 1536, wqkvT, 512, 1536);
            k_transpose_cvt<<<dim3(16, 16), dim3(32, 8), 0, stream>>>(w_out + (size_t)i * 512 * 512,  woutT, 512, 512);
            k_transpose_cvt<<<dim3(64, 16), dim3(32, 8), 0, stream>>>(w1    + (size_t)i * 512 * 2048, w1T,   512, 2048);
            k_transpose_cvt<<<dim3(16, 64), dim3(32, 8), 0, stream>>>(w2    + (size_t)i * 2048 * 512, w2T,   2048, 512);
        }

        k_layernorm<<<dim3(M_TOK / 4), dim3(256), 0, stream>>>(x_f32, ln1_s + i * 512, ln1_b + i * 512, ln_out);
        k_gemm128b<0><<<dim3(12, 64), dim3(256), 0, stream>>>(ln_out, wqkvT, nullptr, qkv,
                                                              M_TOK, 1536, 512);
        if (split_ok){
            k_flash_split<<<dim3(1024), dim3(256), 0, stream>>>(qkv, Opart, lpart);
            k_combine<<<dim3(2048), dim3(256), 0, stream>>>(Opart, lpart, attn_out);
        } else {
            k_flash<<<dim3(512), dim3(256), 0, stream>>>(qkv, attn_out);
        }
        k_gemm128_res<<<dim3(4, 64), dim3(256), 0, stream>>>(attn_out, woutT, b_out + i * 512, x_f32,
                                                             M_TOK, 512, 512);
        k_layernorm<<<dim3(M_TOK / 4), dim3(256), 0, stream>>>(x_f32, ln2_s + i * 512, ln2_b + i * 512, ln_out);
        k_gemm128b<1><<<dim3(16, 64), dim3(256), 0, stream>>>(ln_out, w1T, b1 + i * 2048, mlp_h,
                                                              M_TOK, 2048, 512);
        k_gemm128_res<<<dim3(4, 64), dim3(256), 0, stream>>>(mlp_h, w2T, b2 + i * 512, x_f32,
                                                             M_TOK, 512, 2048);
    }
    hipMemcpyAsync(out, x_f32, x_bytes, hipMemcpyDeviceToDevice, stream);
}

// Round 9
// 1073.503 us; speedup vs baseline: 1.0423x; 1.0278x over previous
//
#include <hip/hip_runtime.h>
#include <cstdint>
#include <cstddef>

#define M_TOK 8192
#define DIMM  512
#define HEADS 8
#define DH    64
#define MLPD  2048
#define DEPTH 6

typedef unsigned short u16;
typedef unsigned int   u32;
typedef __attribute__((ext_vector_type(8))) short short8;   // 8 bf16 (4 VGPRs)
typedef __attribute__((ext_vector_type(4))) float f32x4;    // 4 fp32 acc

__device__ __forceinline__ float bf2f(u16 u){ return __uint_as_float(((u32)u) << 16); }
__device__ __forceinline__ u16 f2bf(float f){
    u32 x = __float_as_uint(f);
    u32 r = x + 0x7fffu + ((x >> 16) & 1u);   // RNE
    return (u16)(r >> 16);
}
// packed f32x2 -> bf16x2 (RNE), 1 instr for 2 converts
__device__ __forceinline__ u32 cvt_pk_bf16(float a, float b){
    u32 r;
    asm("v_cvt_pk_bf16_f32 %0, %1, %2" : "=v"(r) : "v"(a), "v"(b));
    return r;
}
// async global->LDS, 16B per lane; lds dest wave-uniform base (+lane*16 implicit); global addr per-lane
__device__ __forceinline__ void async16(const u16* g, u16* l){
    __builtin_amdgcn_global_load_lds(
        (const __attribute__((address_space(1))) void*)(uintptr_t)(const void*)g,
        (__attribute__((address_space(3))) void*)(u32)(uintptr_t)(void*)l,
        16, 0, 0);
}
// XCD-grouping block swizzle: put all x-blocks sharing an A-row-panel on one XCD.
__device__ __forceinline__ void xcd_swizzle(int& bx, int& by){
    int nbx = gridDim.x, nby = gridDim.y;
    if ((nby & 7) == 0){
        int i = by * nbx + bx;
        int xcd = i & 7, j = i >> 3, ypg = nby >> 3;
        int yq = j / nbx;
        by = xcd * ypg + yq;
        bx = j - yq * nbx;
    }
}

// ---------------- weight transpose + cvt: fp32 in[R][C] -> bf16 out[C][R], z layers ----------------
__global__ void k_transpose_cvt(const float* __restrict__ in, u16* __restrict__ out, int R, int C){
    __shared__ u16 tile[32][33];
    size_t zoff = (size_t)blockIdx.z * R * C;
    in += zoff; out += zoff;
    int c0 = blockIdx.x * 32, r0 = blockIdx.y * 32;
    int tx = threadIdx.x, ty = threadIdx.y;           // (32, 8)
    #pragma unroll
    for (int i = 0; i < 32; i += 8)
        tile[ty + i][tx] = f2bf(in[(size_t)(r0 + ty + i) * C + c0 + tx]);
    __syncthreads();
    #pragma unroll
    for (int i = 0; i < 32; i += 8)
        out[(size_t)(c0 + ty + i) * R + r0 + tx] = tile[tx][ty + i];
}

// ---------------- LayerNorm: fp32 x row -> bf16 out; 4 rows/block, 1 wave/row ----------------
__global__ __launch_bounds__(256) void k_layernorm(const float* __restrict__ x,
                                                   const float* __restrict__ s,
                                                   const float* __restrict__ b,
                                                   u16* __restrict__ out){
    int row = blockIdx.x * 4 + (threadIdx.x >> 6);
    int lane = threadIdx.x & 63;
    const float* xp = x + (size_t)row * DIMM + lane * 8;
    float v[8];
    #pragma unroll
    for (int c = 0; c < 8; c++) v[c] = xp[c];
    float sum = 0.f, sq = 0.f;
    #pragma unroll
    for (int c = 0; c < 8; c++){ sum += v[c]; sq += v[c] * v[c]; }
    #pragma unroll
    for (int m = 32; m >= 1; m >>= 1){
        sum += __shfl_xor(sum, m);
        sq  += __shfl_xor(sq,  m);
    }
    float mu  = sum * (1.f / DIMM);
    float var = sq * (1.f / DIMM) - mu * mu;
    float rs  = rsqrtf(var + 1e-5f);
    u16* op = out + (size_t)row * DIMM + lane * 8;
    #pragma unroll
    for (int c = 0; c < 8; c++){
        int col = lane * 8 + c;
        op[c] = f2bf((v[c] - mu) * rs * s[col] + b[col]);
    }
}

// Abramowitz-Stegun 7.1.26 erf (abs err 1.5e-7): rcp + 5 FMA + exp2, no branches.
__device__ __forceinline__ float erf_as(float x){
    float ax = fabsf(x);
    float t  = __builtin_amdgcn_rcpf(fmaf(0.3275911f, ax, 1.f));
    float y  = fmaf(fmaf(fmaf(fmaf(1.061405429f, t, -1.453152027f), t,
                              1.421413741f), t, -0.284496736f), t, 0.254829592f) * t;
    float e  = exp2f(-ax * ax * 1.4426950408889634f);
    float r  = 1.f - y * e;
    return copysignf(r, x);
}
__device__ __forceinline__ float gelu_exact(float v){
    return 0.5f * v * (1.f + erf_as(v * 0.70710678118654752f));
}

#define LDT64 72   // padded stride for epilogue LDS scratch only

// ============ 128x128-tile GEMM, BK=64, dbuf + counted-vmcnt raw-barrier pipeline + T2 swizzle ========
// (unchanged from round 6 — verified)
template<int MODE>
__global__ __launch_bounds__(256) void k_gemm128b(const u16* __restrict__ A,
                                                  const u16* __restrict__ Bt,
                                                  const float* __restrict__ bias,
                                                  u16* __restrict__ Cout,
                                                  int M, int N, int K){
    __shared__ u16 As[2][128 * 64];
    __shared__ u16 Bs[2][128 * 64];
    int bx = blockIdx.x, by = blockIdx.y;
    xcd_swizzle(bx, by);
    int m0 = by * 128, n0 = bx * 128;
    int t = threadIdx.x;
    int w = t >> 6, lane = t & 63;
    int mi = lane & 15, quad = lane >> 4;
    int wr = w >> 1, wc = w & 1;
    int sw = mi & 7;                      // read-side XOR key (row&7 == mi&7 for fragment rows)

    int grow = lane >> 3;
    int gcol = (((lane & 7) ^ grow) & 7) * 8;
    const u16* agl = A  + (size_t)(m0 + w * 32 + grow) * K + gcol;
    const u16* bgl = Bt + (size_t)(n0 + w * 32 + grow) * K + gcol;

    f32x4 acc[4][4];
    #pragma unroll
    for (int mt = 0; mt < 4; mt++)
        #pragma unroll
        for (int nt = 0; nt < 4; nt++) acc[mt][nt] = (f32x4){0.f, 0.f, 0.f, 0.f};

    int nt_k = K >> 6;
    {   // prologue: stage tile 0 -> buf 0 (8 loads/wave in flight)
        u16* asl = &As[0][(w * 32) * 64];
        u16* bsl = &Bs[0][(w * 32) * 64];
        #pragma unroll
        for (int i = 0; i < 4; i++){
            async16(agl + (size_t)(i * 8) * K, asl + i * 8 * 64);
            async16(bgl + (size_t)(i * 8) * K, bsl + i * 8 * 64);
        }
    }

    for (int td = 0; td < nt_k; td++){
        int cur = td & 1;
        if (td + 1 < nt_k){                    // stage next tile, then wait ONLY for tile td
            int k0 = (td + 1) << 6;
            u16* asl = &As[cur ^ 1][(w * 32) * 64];
            u16* bsl = &Bs[cur ^ 1][(w * 32) * 64];
            #pragma unroll
            for (int i = 0; i < 4; i++){
                async16(agl + (size_t)(i * 8) * K + k0, asl + i * 8 * 64);
                async16(bgl + (size_t)(i * 8) * K + k0, bsl + i * 8 * 64);
            }
            asm volatile("s_waitcnt vmcnt(8)" ::: "memory");
        } else {
            asm volatile("s_waitcnt vmcnt(0)" ::: "memory");
        }
        __builtin_amdgcn_s_barrier();          // all waves' tile-td loads landed
        __builtin_amdgcn_sched_barrier(0);
        const u16* Ab = &As[cur][0];
        const u16* Bb = &Bs[cur][0];
        #pragma unroll
        for (int kk = 0; kk < 64; kk += 32){
            const int kc = kk >> 3;            // logical chunk base: 0 or 4
            short8 af[4], bf[4];
            #pragma unroll
            for (int mt = 0; mt < 4; mt++)
                af[mt] = *(const short8*)&Ab[(wr * 64 + mt * 16 + mi) * 64 + (((quad + kc) ^ sw) * 8)];
            #pragma unroll
            for (int nt = 0; nt < 4; nt++)
                bf[nt] = *(const short8*)&Bb[(wc * 64 + nt * 16 + mi) * 64 + (((quad + kc) ^ sw) * 8)];
            #pragma unroll
            for (int mt = 0; mt < 4; mt++)
                #pragma unroll
                for (int nt = 0; nt < 4; nt++)
                    acc[mt][nt] = __builtin_amdgcn_mfma_f32_16x16x32_bf16(af[mt], bf[nt], acc[mt][nt], 0, 0, 0);
        }
        __builtin_amdgcn_sched_barrier(0);
        __builtin_amdgcn_s_barrier();          // all reads of buf[cur] done -> safe to overwrite next iter
    }

    // ---- coalesced epilogue: per-wave C-subtile through LDS (wave-private scratch over As) ----
    float bv[4];
    if (MODE == 1){
        #pragma unroll
        for (int nt = 0; nt < 4; nt++) bv[nt] = bias[n0 + wc * 64 + nt * 16 + mi];
    }
    u16* cs = ((u16*)As) + w * 16 * LDT64;     // 16x72 u16 per wave
    int erow = lane >> 2, ecol = (lane & 3) * 16;
    #pragma unroll
    for (int mt = 0; mt < 4; mt++){
        #pragma unroll
        for (int nt = 0; nt < 4; nt++)
            #pragma unroll
            for (int r = 0; r < 4; r++){
                float v = acc[mt][nt][r];
                if (MODE == 1) v = gelu_exact(v + bv[nt]);
                cs[(quad * 4 + r) * LDT64 + nt * 16 + mi] = f2bf(v);
            }
        uint4 c0 = *(const uint4*)&cs[erow * LDT64 + ecol];
        uint4 c1 = *(const uint4*)&cs[erow * LDT64 + ecol + 8];
        u16* cp = Cout + (size_t)(m0 + wr * 64 + mt * 16 + erow) * N + n0 + wc * 64 + ecol;
        *(uint4*)cp       = c0;
        *(uint4*)(cp + 8) = c1;
    }
}

// ============ 128x128-tile GEMM, same pipeline+swizzle, fp32 residual RMW epilogue (unchanged) ========
__global__ __launch_bounds__(256) void k_gemm128_res(const u16* __restrict__ A,
                                                     const u16* __restrict__ Bt,
                                                     const float* __restrict__ bias,
                                                     float* __restrict__ xres,
                                                     int M, int N, int K){
    __shared__ u16 As[2][128 * 64];
    __shared__ u16 Bs[2][128 * 64];
    int bx = blockIdx.x, by = blockIdx.y;
    xcd_swizzle(bx, by);
    int m0 = by * 128, n0 = bx * 128;
    int t = threadIdx.x;
    int w = t >> 6, lane = t & 63;
    int mi = lane & 15, quad = lane >> 4;
    int wr = w >> 1, wc = w & 1;
    int sw = mi & 7;

    int grow = lane >> 3;
    int gcol = (((lane & 7) ^ grow) & 7) * 8;
    const u16* agl = A  + (size_t)(m0 + w * 32 + grow) * K + gcol;
    const u16* bgl = Bt + (size_t)(n0 + w * 32 + grow) * K + gcol;

    f32x4 acc[4][4];
    #pragma unroll
    for (int mt = 0; mt < 4; mt++)
        #pragma unroll
        for (int nt = 0; nt < 4; nt++) acc[mt][nt] = (f32x4){0.f, 0.f, 0.f, 0.f};

    int nt_k = K >> 6;
    {   // prologue
        u16* asl = &As[0][(w * 32) * 64];
        u16* bsl = &Bs[0][(w * 32) * 64];
        #pragma unroll
        for (int i = 0; i < 4; i++){
            async16(agl + (size_t)(i * 8) * K, asl + i * 8 * 64);
            async16(bgl + (size_t)(i * 8) * K, bsl + i * 8 * 64);
        }
    }

    for (int td = 0; td < nt_k; td++){
        int cur = td & 1;
        if (td + 1 < nt_k){
            int k0 = (td + 1) << 6;
            u16* asl = &As[cur ^ 1][(w * 32) * 64];
            u16* bsl = &Bs[cur ^ 1][(w * 32) * 64];
            #pragma unroll
            for (int i = 0; i < 4; i++){
                async16(agl + (size_t)(i * 8) * K + k0, asl + i * 8 * 64);
                async16(bgl + (size_t)(i * 8) * K + k0, bsl + i * 8 * 64);
            }
            asm volatile("s_waitcnt vmcnt(8)" ::: "memory");
        } else {
            asm volatile("s_waitcnt vmcnt(0)" ::: "memory");
        }
        __builtin_amdgcn_s_barrier();
        __builtin_amdgcn_sched_barrier(0);
        const u16* Ab = &As[cur][0];
        const u16* Bb = &Bs[cur][0];
        #pragma unroll
        for (int kk = 0; kk < 64; kk += 32){
            const int kc = kk >> 3;
            short8 af[4], bf[4];
            #pragma unroll
            for (int mt = 0; mt < 4; mt++)
                af[mt] = *(const short8*)&Ab[(wr * 64 + mt * 16 + mi) * 64 + (((quad + kc) ^ sw) * 8)];
            #pragma unroll
            for (int nt = 0; nt < 4; nt++)
                bf[nt] = *(const short8*)&Bb[(wc * 64 + nt * 16 + mi) * 64 + (((quad + kc) ^ sw) * 8)];
            #pragma unroll
            for (int mt = 0; mt < 4; mt++)
                #pragma unroll
                for (int nt = 0; nt < 4; nt++)
                    acc[mt][nt] = __builtin_amdgcn_mfma_f32_16x16x32_bf16(af[mt], bf[nt], acc[mt][nt], 0, 0, 0);
        }
        __builtin_amdgcn_sched_barrier(0);
        __builtin_amdgcn_s_barrier();
    }

    // ---- coalesced fp32 RMW epilogue through LDS (per-wave 16x72 fp32 region over As) ----
    float bv[4];
    #pragma unroll
    for (int nt = 0; nt < 4; nt++) bv[nt] = bias[n0 + wc * 64 + nt * 16 + mi];
    float* cs = ((float*)As) + w * 16 * LDT64;
    int erow = lane >> 2, ecol = (lane & 3) * 16;
    #pragma unroll
    for (int mt = 0; mt < 4; mt++){
        #pragma unroll
        for (int nt = 0; nt < 4; nt++)
            #pragma unroll
            for (int r = 0; r < 4; r++)
                cs[(quad * 4 + r) * LDT64 + nt * 16 + mi] = acc[mt][nt][r] + bv[nt];
        float* xp = xres + (size_t)(m0 + wr * 64 + mt * 16 + erow) * N + n0 + wc * 64 + ecol;
        #pragma unroll
        for (int j = 0; j < 4; j++){
            float4 cv = *(const float4*)&cs[erow * LDT64 + ecol + j * 4];
            float4 xv = *(const float4*)(xp + j * 4);
            xv.x += cv.x; xv.y += cv.y; xv.z += cv.z; xv.w += cv.w;
            *(float4*)(xp + j * 4) = xv;
        }
    }
}

// ---------------- MFMA flash attention ----------------
#define LDK 72
#define LDP 40                          // Ps chunk stride: 32 keys + 8 pad (16B-aligned rows)
#define C1_LOG2E 0.18033688011112042f   // 0.125 * log2(e)
#define C2_LOG2E 11.541560327111707f    // 8 * log2(e)
#define OSPLIT (M_TOK * 512)            // elems per split O buffer (bf16)
#define LSPLIT (M_TOK * 8)              // floats per split l buffer

// split-K flash v4: swapped QK (z = mfma(K, Q)) so each lane's z[0..3] = 4 CONSECUTIVE KEYS of one
// q-row -> Ps store is a single ds_write_b64. V staged via 4key x 4dim register transpose ->
// 4x ds_write_b64 (was 16x b16). DS wave-ops/tile: ~70 -> ~34 (kernel was LDS-issue bound).
__global__ __launch_bounds__(256) void k_flash_split(const u16* __restrict__ qkv,
                                                     u16* __restrict__ Opart,
                                                     float* __restrict__ lpart){
    __shared__ u16 Ks[64 * LDK];        // [key][dim]
    __shared__ u16 Vt[64 * LDK];        // [dim][key]
    __shared__ u16 Ps[4][32 * LDP];     // per-wave P chunk [q32][32 keys]
    // XCD swizzle: nwg=1024, cpx=128 -> XCD k owns batch k (both splits co-located)
    int wg = (blockIdx.x & 7) * 128 + (blockIdx.x >> 3);
    int qt = wg & 7, h = (wg >> 3) & 7, sp = (wg >> 6) & 1, b = wg >> 7;
    int t = threadIdx.x;
    int w = t >> 6, lane = t & 63;
    int mi = lane & 15, quad = lane >> 4;

    const u16* base = qkv + ((size_t)b * 1024) * 1536;
    int hoff = h * 64;

    short8 ones;
    #pragma unroll
    for (int i = 0; i < 8; i++) ones[i] = (short)0x3F80;   // bf16 1.0

    short8 qf[2][2];
    #pragma unroll
    for (int qh = 0; qh < 2; qh++){
        int qrow = qt * 128 + w * 32 + qh * 16 + mi;
        const u16* qp = base + (size_t)qrow * 1536 + hoff + quad * 8;
        qf[qh][0] = *(const short8*)(qp);
        qf[qh][1] = *(const short8*)(qp + 32);
    }

    f32x4 o[2][4];
    f32x4 lacc[2];
    #pragma unroll
    for (int qh = 0; qh < 2; qh++){
        #pragma unroll
        for (int nb = 0; nb < 4; nb++) o[qh][nb] = (f32x4){0.f, 0.f, 0.f, 0.f};
        lacc[qh] = (f32x4){0.f, 0.f, 0.f, 0.f};
    }

    int kkey = t >> 2, kseg = t & 3;
    const u16* kgp = base + (size_t)kkey * 1536 + 512 + hoff + kseg * 16;
    // V staging: thread owns keys vkey0..+3 x dims vdg..+3 (4x4 register transpose)
    int vkey0 = (lane & 15) * 4;
    int vdg = w * 16 + quad * 4;
    const u16* vgp = base + (size_t)vkey0 * 1536 + 1024 + hoff + vdg;

    int kt0 = sp * 8;
    size_t koff0 = (size_t)kt0 * 64 * 1536;
    uint4 kv0 = *(const uint4*)(kgp + koff0);
    uint4 kv1 = *(const uint4*)(kgp + koff0 + 8);
    uint2 vv[4];
    #pragma unroll
    for (int i = 0; i < 4; i++)
        vv[i] = *(const uint2*)(vgp + koff0 + (size_t)i * 1536);

    for (int kt = kt0; kt < kt0 + 8; kt++){
        __syncthreads();                              // prev tile's LDS reads done
        *(uint4*)&Ks[kkey * LDK + kseg * 16]     = kv0;
        *(uint4*)&Ks[kkey * LDK + kseg * 16 + 8] = kv1;
        // 4x4 register transpose: vv[i] = dims vdg..+3 of key vkey0+i
        {
            const u16* ev = (const u16*)vv;
            #pragma unroll
            for (int j = 0; j < 4; j++){
                uint2 pk;
                pk.x = (u32)ev[0 * 4 + j] | ((u32)ev[1 * 4 + j] << 16);
                pk.y = (u32)ev[2 * 4 + j] | ((u32)ev[3 * 4 + j] << 16);
                *(uint2*)&Vt[(vdg + j) * LDK + vkey0] = pk;   // b64: 4 keys packed
            }
        }
        __syncthreads();

        if (kt < kt0 + 7){                            // issue next tile's loads under MFMA
            size_t koff = (size_t)(kt + 1) * 64 * 1536;
            kv0 = *(const uint4*)(kgp + koff);
            kv1 = *(const uint4*)(kgp + koff + 8);
            #pragma unroll
            for (int i = 0; i < 4; i++)
                vv[i] = *(const uint2*)(vgp + koff + (size_t)i * 1536);
        }

        // ---- two 32-key chunks: swapped QK -> P chunk (b64 stores) -> partial PV ----
        #pragma unroll
        for (int kh = 0; kh < 2; kh++){
            short8 kb[2][2];
            #pragma unroll
            for (int nbl = 0; nbl < 2; nbl++){
                int nb = kh * 2 + nbl;
                kb[nbl][0] = *(const short8*)&Ks[(nb * 16 + mi) * LDK + quad * 8];
                kb[nbl][1] = *(const short8*)&Ks[(nb * 16 + mi) * LDK + quad * 8 + 32];
            }
            // z = mfma(K, Q): z[r] = S[key = nb*16 + quad*4 + r][q = qh*16 + mi]
            #pragma unroll
            for (int qh = 0; qh < 2; qh++){
                #pragma unroll
                for (int nbl = 0; nbl < 2; nbl++){
                    f32x4 z = (f32x4){0.f, 0.f, 0.f, 0.f};
                    z = __builtin_amdgcn_mfma_f32_16x16x32_bf16(kb[nbl][0], qf[qh][0], z, 0, 0, 0);
                    z = __builtin_amdgcn_mfma_f32_16x16x32_bf16(kb[nbl][1], qf[qh][1], z, 0, 0, 0);
                    float e0 = exp2f(fmaf(z[0], C1_LOG2E, -C2_LOG2E));
                    float e1 = exp2f(fmaf(z[1], C1_LOG2E, -C2_LOG2E));
                    float e2 = exp2f(fmaf(z[2], C1_LOG2E, -C2_LOG2E));
                    float e3 = exp2f(fmaf(z[3], C1_LOG2E, -C2_LOG2E));
                    uint2 pk;
                    pk.x = cvt_pk_bf16(e0, e1);
                    pk.y = cvt_pk_bf16(e2, e3);
                    // P row q = qh*16+mi, cols (chunk-local) nbl*16 + quad*4 .. +3: one b64
                    *(uint2*)&Ps[w][(qh * 16 + mi) * LDP + nbl * 16 + quad * 4] = pk;
                }
            }
            // V fragments for this chunk (keys kh*32..+31, all 4 dim-blocks)
            short8 vb[4];
            #pragma unroll
            for (int nb = 0; nb < 4; nb++)
                vb[nb] = *(const short8*)&Vt[(nb * 16 + mi) * LDK + kh * 32 + quad * 8];
            // partial PV + l (wave-private Ps: in-wave DS ordering, no barrier)
            #pragma unroll
            for (int qh = 0; qh < 2; qh++){
                const short8 a = *(const short8*)&Ps[w][(qh * 16 + mi) * LDP + quad * 8];
                #pragma unroll
                for (int nb = 0; nb < 4; nb++)
                    o[qh][nb] = __builtin_amdgcn_mfma_f32_16x16x32_bf16(a, vb[nb], o[qh][nb], 0, 0, 0);
                lacc[qh] = __builtin_amdgcn_mfma_f32_16x16x32_bf16(a, ones, lacc[qh], 0, 0, 0);
            }
        }
    }
    u16* Ob = Opart + (size_t)sp * OSPLIT;
    float* lb2 = lpart + (size_t)sp * LSPLIT;
    #pragma unroll
    for (int qh = 0; qh < 2; qh++){
        int grow0 = b * 1024 + qt * 128 + w * 32 + qh * 16;
        u16* op = Ob + (size_t)grow0 * 512 + hoff;
        #pragma unroll
        for (int nb = 0; nb < 4; nb++){
            u32 c01 = cvt_pk_bf16(o[qh][nb][0], o[qh][nb][1]);
            u32 c23 = cvt_pk_bf16(o[qh][nb][2], o[qh][nb][3]);
            u16* cp = op + (size_t)(quad * 4) * 512 + nb * 16 + mi;
            cp[0]       = (u16)c01;
            cp[512]     = (u16)(c01 >> 16);
            cp[2 * 512] = (u16)c23;
            cp[3 * 512] = (u16)(c23 >> 16);
        }
        if (mi == 0){
            #pragma unroll
            for (int r = 0; r < 4; r++)
                lb2[(size_t)(grow0 + quad * 4 + r) * 8 + h] = lacc[qh][r];
        }
    }
}

// combine: out = bf16((O0+O1)/(l0+l1)); partials bf16; 8 elems/thread, fully coalesced
__global__ __launch_bounds__(256) void k_combine(const u16* __restrict__ Opart,
                                                 const float* __restrict__ lpart,
                                                 u16* __restrict__ out){
    int tid = blockIdx.x * 256 + threadIdx.x;
    size_t basei = (size_t)tid * 8;
    int row = (int)(basei >> 9), col = (int)(basei & 511), h = col >> 6;
    float l = lpart[(size_t)row * 8 + h] + lpart[(size_t)LSPLIT + (size_t)row * 8 + h];
    float inv = 1.f / l;
    uint4 a = *(const uint4*)(Opart + basei);
    uint4 bq = *(const uint4*)(Opart + (size_t)OSPLIT + basei);
    const u32* au = (const u32*)&a;
    const u32* bu = (const u32*)&bq;
    uint4 r;
    u32* ru = (u32*)&r;
    #pragma unroll
    for (int j = 0; j < 4; j++){
        float s0 = bf2f((u16)au[j])         + bf2f((u16)bu[j]);
        float s1 = bf2f((u16)(au[j] >> 16)) + bf2f((u16)(bu[j] >> 16));
        ru[j] = cvt_pk_bf16(s0 * inv, s1 * inv);
    }
    *(uint4*)(out + basei) = r;
}

// fallback single-pass flash, used when workspace too small for partials
__global__ __launch_bounds__(256) void k_flash(const u16* __restrict__ qkv, u16* __restrict__ out){
    __shared__ u16 Ks[64 * LDK];
    __shared__ u16 Vt[64 * LDK];
    __shared__ u16 Ps[4][32 * LDK];
    int wg = (blockIdx.x & 7) * 64 + (blockIdx.x >> 3);
    int qt = wg & 7, h = (wg >> 3) & 7, b = wg >> 6;
    int t = threadIdx.x;
    int w = t >> 6, lane = t & 63;
    int mi = lane & 15, quad = lane >> 4;

    const u16* base = qkv + ((size_t)b * 1024) * 1536;
    int hoff = h * 64;

    short8 ones;
    #pragma unroll
    for (int i = 0; i < 8; i++) ones[i] = (short)0x3F80;

    short8 qf[2][2];
    #pragma unroll
    for (int qh = 0; qh < 2; qh++){
        int qrow = qt * 128 + w * 32 + qh * 16 + mi;
        const u16* qp = base + (size_t)qrow * 1536 + hoff + quad * 8;
        qf[qh][0] = *(const short8*)(qp);
        qf[qh][1] = *(const short8*)(qp + 32);
    }
    f32x4 o[2][4];
    f32x4 lacc[2];
    #pragma unroll
    for (int qh = 0; qh < 2; qh++){
        #pragma unroll
        for (int nb = 0; nb < 4; nb++) o[qh][nb] = (f32x4){0.f, 0.f, 0.f, 0.f};
        lacc[qh] = (f32x4){0.f, 0.f, 0.f, 0.f};
    }
    int kkey = t >> 2, kseg = t & 3;
    const u16* kgp = base + (size_t)kkey * 1536 + 512 + hoff + kseg * 16;
    int vkey = lane, vdg = w;
    const u16* vgp = base + (size_t)vkey * 1536 + 1024 + hoff + vdg * 16;

    uint4 kv0 = *(const uint4*)(kgp);
    uint4 kv1 = *(const uint4*)(kgp + 8);
    uint4 vv0 = *(const uint4*)(vgp);
    uint4 vv1 = *(const uint4*)(vgp + 8);

    for (int kt = 0; kt < 16; kt++){
        __syncthreads();
        *(uint4*)&Ks[kkey * LDK + kseg * 16]     = kv0;
        *(uint4*)&Ks[kkey * LDK + kseg * 16 + 8] = kv1;
        u16 vtmp[16];
        *(uint4*)&vtmp[0] = vv0;
        *(uint4*)&vtmp[8] = vv1;
        #pragma unroll
        for (int i = 0; i < 16; i++)
            Vt[(vdg * 16 + i) * LDK + vkey] = vtmp[i];
        __syncthreads();
        if (kt < 15){
            size_t koff = (size_t)(kt + 1) * 64 * 1536;
            kv0 = *(const uint4*)(kgp + koff);
            kv1 = *(const uint4*)(kgp + koff + 8);
            vv0 = *(const uint4*)(vgp + koff);
            vv1 = *(const uint4*)(vgp + koff + 8);
        }
        short8 kb[4][2];
        #pragma unroll
        for (int nb = 0; nb < 4; nb++){
            kb[nb][0] = *(const short8*)&Ks[(nb * 16 + mi) * LDK + quad * 8];
            kb[nb][1] = *(const short8*)&Ks[(nb * 16 + mi) * LDK + quad * 8 + 32];
        }
        #pragma unroll
        for (int qh = 0; qh < 2; qh++){
            #pragma unroll
            for (int nb = 0; nb < 4; nb++){
                f32x4 z = (f32x4){0.f, 0.f, 0.f, 0.f};
                z = __builtin_amdgcn_mfma_f32_16x16x32_bf16(qf[qh][0], kb[nb][0], z, 0, 0, 0);
                z = __builtin_amdgcn_mfma_f32_16x16x32_bf16(qf[qh][1], kb[nb][1], z, 0, 0, 0);
                float e0 = exp2f(fmaf(z[0], C1_LOG2E, -C2_LOG2E));
                float e1 = exp2f(fmaf(z[1], C1_LOG2E, -C2_LOG2E));
                float e2 = exp2f(fmaf(z[2], C1_LOG2E, -C2_LOG2E));
                float e3 = exp2f(fmaf(z[3], C1_LOG2E, -C2_LOG2E));
                u32 p01 = cvt_pk_bf16(e0, e1);
                u32 p23 = cvt_pk_bf16(e2, e3);
                u16* pp = &Ps[w][(qh * 16 + quad * 4) * LDK + nb * 16 + mi];
                pp[0]       = (u16)p01;
                pp[LDK]     = (u16)(p01 >> 16);
                pp[2 * LDK] = (u16)p23;
                pp[3 * LDK] = (u16)(p23 >> 16);
            }
        }
        short8 vb[4][2];
        #pragma unroll
        for (int nb = 0; nb < 4; nb++){
            vb[nb][0] = *(const short8*)&Vt[(nb * 16 + mi) * LDK + quad * 8];
            vb[nb][1] = *(const short8*)&Vt[(nb * 16 + mi) * LDK + quad * 8 + 32];
        }
        #pragma unroll
        for (int qh = 0; qh < 2; qh++){
            const short8 a0 = *(const short8*)&Ps[w][(qh * 16 + mi) * LDK + quad * 8];
            const short8 a1 = *(const short8*)&Ps[w][(qh * 16 + mi) * LDK + quad * 8 + 32];
            #pragma unroll
            for (int nb = 0; nb < 4; nb++){
                o[qh][nb] = __builtin_amdgcn_mfma_f32_16x16x32_bf16(a0, vb[nb][0], o[qh][nb], 0, 0, 0);
                o[qh][nb] = __builtin_amdgcn_mfma_f32_16x16x32_bf16(a1, vb[nb][1], o[qh][nb], 0, 0, 0);
            }
            lacc[qh] = __builtin_amdgcn_mfma_f32_16x16x32_bf16(a0, ones, lacc[qh], 0, 0, 0);
            lacc[qh] = __builtin_amdgcn_mfma_f32_16x16x32_bf16(a1, ones, lacc[qh], 0, 0, 0);
        }
    }
    #pragma unroll
    for (int qh = 0; qh < 2; qh++){
        float invl[4];
        #pragma unroll
        for (int r = 0; r < 4; r++) invl[r] = 1.f / lacc[qh][r];
        u16* op = out + ((size_t)b * 1024 + qt * 128 + w * 32 + qh * 16) * 512 + hoff;
        #pragma unroll
        for (int nb = 0; nb < 4; nb++){
            u32 c01 = cvt_pk_bf16(o[qh][nb][0] * invl[0], o[qh][nb][1] * invl[1]);
            u32 c23 = cvt_pk_bf16(o[qh][nb][2] * invl[2], o[qh][nb][3] * invl[3]);
            u16* cp = op + (size_t)(quad * 4) * 512 + nb * 16 + mi;
            cp[0]       = (u16)c01;
            cp[512]     = (u16)(c01 >> 16);
            cp[2 * 512] = (u16)c23;
            cp[3 * 512] = (u16)(c23 >> 16);
        }
    }
}

// ---------------- host launch ----------------
extern "C" void kernel_launch(void* const* d_in, const int* in_sizes, int n_in,
                              void* d_out, int out_size, void* d_ws, size_t ws_size,
                              hipStream_t stream){
    const float* x_in  = (const float*)d_in[0];
    const float* ln1_s = (const float*)d_in[1];
    const float* ln1_b = (const float*)d_in[2];
    const float* w_qkv = (const float*)d_in[3];
    const float* w_out = (const float*)d_in[4];
    const float* b_out = (const float*)d_in[5];
    const float* ln2_s = (const float*)d_in[6];
    const float* ln2_b = (const float*)d_in[7];
    const float* w1    = (const float*)d_in[8];
    const float* b1    = (const float*)d_in[9];
    const float* w2    = (const float*)d_in[10];
    const float* b2    = (const float*)d_in[11];
    float* out = (float*)d_out;

    char* ws = (char*)d_ws;
    float* x_f32 = (float*)ws;   ws += (size_t)M_TOK * DIMM * 4;      // 16 MB fp32 residual
    u16* bufA    = (u16*)ws;     ws += (size_t)M_TOK * DIMM * 2;      // 8 MB  (ln_out / attn_out)
    u16* bufB    = (u16*)ws;     ws += (size_t)M_TOK * MLPD * 2;      // 32 MB (qkv / mlp_h)

    size_t per_layer_w = (size_t)(1536 + 512 + 2048 + 2048) * 512;    // u16 elems (6.3 MB)
    size_t split_bytes = (size_t)2 * OSPLIT * 2 + (size_t)2 * LSPLIT * 4;  // 17.3 MB (bf16 O)
    size_t base_used = (size_t)(ws - (char*)d_ws);

    bool split_ok = ws_size >= base_used + split_bytes + per_layer_w * 2;
    u16* Opart   = (u16*)ws;
    float* lpart = (float*)(ws + (size_t)2 * OSPLIT * 2);
    u16* wbase = split_ok ? (u16*)(ws + split_bytes) : (u16*)ws;
    size_t wb_off = (size_t)((char*)wbase - (char*)d_ws);
    bool big = ws_size >= wb_off + per_layer_w * 2 * DEPTH;

    u16* ln_out   = bufA;
    u16* attn_out = bufA;
    u16* qkv      = bufB;
    u16* mlp_h    = bufB;

    size_t x_bytes = (size_t)M_TOK * DIMM * sizeof(float);
    hipMemcpyAsync(x_f32, x_in, x_bytes, hipMemcpyDeviceToDevice, stream);

    const size_t off_qkv = 0;
    const size_t off_out = (size_t)1536 * 512;
    const size_t off_w1  = off_out + (size_t)512 * 512;
    const size_t off_w2  = off_w1 + (size_t)2048 * 512;

    if (big){
        k_transpose_cvt<<<dim3(48, 16, 6), dim3(32, 8), 0, stream>>>(w_qkv, wbase + off_qkv * DEPTH, 512, 1536);
        k_transpose_cvt<<<dim3(16, 16, 6), dim3(32, 8), 0, stream>>>(w_out, wbase + off_out * DEPTH, 512, 512);
        k_transpose_cvt<<<dim3(64, 16, 6), dim3(32, 8), 0, stream>>>(w1,    wbase + off_w1  * DEPTH, 512, 2048);
        k_transpose_cvt<<<dim3(16, 64, 6), dim3(32, 8), 0, stream>>>(w2,    wbase + off_w2  * DEPTH, 2048, 512);
    }

    for (int i = 0; i < DEPTH; i++){
        u16 *wqkvT, *woutT, *w1T, *w2T;
        if (big){
            wqkvT = wbase + off_qkv * DEPTH + (size_t)i * 1536 * 512;
            woutT = wbase + off_out * DEPTH + (size_t)i * 512 * 512;
            w1T   = wbase + off_w1  * DEPTH + (size_t)i * 2048 * 512;
            w2T   = wbase + off_w2  * DEPTH + (size_t)i * 512 * 2048;
        } else {
            wqkvT = wbase + off_qkv; woutT = wbase + off_out;
            w1T   = wbase + off_w1;  w2T   = wbase + off_w2;
            k_transpose_cvt<<<dim3(48, 16), dim3(32, 8), 0, stream>>>(w_qkv + (size_t)i * 512 * 1536, wqkvT, 512, 1536);
            k_transpose_cvt<<<dim3(16, 16), dim3(32, 8), 0, stream>>>(w_out + (size_t)i * 512 * 512,  woutT, 512, 512);
            k_transpose_cvt<<<dim3(64, 16), dim3(32, 8), 0, stream>>>(w1    + (size_t)i * 512 * 2048, w1T,   512, 2048);
            k_transpose_cvt<<<dim3(16, 64), dim3(32, 8), 0, stream>>>(w2    + (size_t)i * 2048 * 512, w2T,   2048, 512);
        }

        k_layernorm<<<dim3(M_TOK / 4), dim3(256), 0, stream>>>(x_f32, ln1_s + i * 512, ln1_b + i * 512, ln_out);
        k_gemm128b<0><<<dim3(12, 64), dim3(256), 0, stream>>>(ln_out, wqkvT, nullptr, qkv,
                                                              M_TOK, 1536, 512);
        if (split_ok){
            k_flash_split<<<dim3(1024), dim3(256), 0, stream>>>(qkv, Opart, lpart);
            k_combine<<<dim3(2048), dim3(256), 0, stream>>>(Opart, lpart, attn_out);
        } else {
            k_flash<<<dim3(512), dim3(256), 0, stream>>>(qkv, attn_out);
        }
        k_gemm128_res<<<dim3(4, 64), dim3(256), 0, stream>>>(attn_out, woutT, b_out + i * 512, x_f32,
                                                             M_TOK, 512, 512);
        k_layernorm<<<dim3(M_TOK / 4), dim3(256), 0, stream>>>(x_f32, ln2_s + i * 512, ln2_b + i * 512, ln_out);
        k_gemm128b<1><<<dim3(16, 64), dim3(256), 0, stream>>>(ln_out, w1T, b1 + i * 2048, mlp_h,
                                                              M_TOK, 2048, 512);
        k_gemm128_res<<<dim3(4, 64), dim3(256), 0, stream>>>(mlp_h, w2T, b2 + i * 512, x_f32,
                                                             M_TOK, 512, 2048);
    }
    hipMemcpyAsync(out, x_f32, x_bytes, hipMemcpyDeviceToDevice, stream);
}